// Round 7
// baseline (1908.912 us; speedup 1.0000x reference)
//
#include <hip/hip_runtime.h>
#include <stdint.h>

typedef unsigned short u16;
typedef __attribute__((ext_vector_type(8))) short bf16x8_t;
typedef __attribute__((ext_vector_type(4))) float f32x4_t;

__device__ __forceinline__ float bl(u16 x) {
  union { unsigned u; float f; } c; c.u = ((unsigned)x) << 16; return c.f;
}
__device__ __forceinline__ u16 fb(float x) {
  union { float f; unsigned u; } c; c.f = x;
  unsigned r = c.u + 0x7fffu + ((c.u >> 16) & 1u);
  return (u16)(r >> 16);
}

__global__ void sentinel_kernel(float* out, int n) {
  int i = blockIdx.x * 256 + threadIdx.x;
  if (i < n) out[i] = 12345.f;
}

// f32 -> bf16 weight conversion
__global__ void cvt_f2b(const float* __restrict__ in, u16* __restrict__ out, int n) {
  int i = blockIdx.x * 256 + threadIdx.x;
  if (i < n) out[i] = fb(in[i]);
}

// ---------------- feature kernels (f32 in / f32 out) ----------------
__global__ void node_feat_kernel(const float* __restrict__ t, const float* __restrict__ tp,
                                 const float* __restrict__ q, const float* __restrict__ qp,
                                 const float* __restrict__ qn, const float* __restrict__ nm,
                                 const float* __restrict__ ns, float* __restrict__ nfeat,
                                 int n_nodes) {
  int n = blockIdx.x * 256 + threadIdx.x;
  if (n >= n_nodes) return;
  float u = t[n];
  float x[9];
  x[0] = u; x[1] = u - tp[n];
  float hq = q[n];
  x[2] = hq; x[3] = hq - qp[n];
#pragma unroll
  for (int j = 0; j < 5; ++j) x[4 + j] = qn[n * 5 + j];
#pragma unroll
  for (int k = 0; k < 9; ++k) nfeat[n * 9 + k] = (x[k] - nm[k]) / ns[k];
}

__global__ void edge_feat_kernel(const int* __restrict__ ei, const float* __restrict__ mp,
                                 const float* __restrict__ u, const float* __restrict__ em,
                                 const float* __restrict__ es, float* __restrict__ efeat,
                                 int n_edges) {
  int e = blockIdx.x * 256 + threadIdx.x;
  if (e >= n_edges) return;
  int s = ei[e], r = ei[n_edges + e];
  float rx = mp[s * 2] - mp[r * 2];
  float ry = mp[s * 2 + 1] - mp[r * 2 + 1];
  float d = sqrtf(rx * rx + ry * ry);
  float rt = u[s] - u[r];
  float x[4] = {rx, ry, d, rt};
#pragma unroll
  for (int k = 0; k < 4; ++k) efeat[e * 4 + k] = (x[k] - em[k]) / es[k];
}

// first encoder layer: out = relu(feat @ w1 + b1), all-f32 math, bf16 out
template <int K>
__global__ void enc1_kernel(const float* __restrict__ feat, const float* __restrict__ w1,
                            const float* __restrict__ b1, u16* __restrict__ out, int M) {
  int gid = blockIdx.x * 256 + threadIdx.x;
  int n = gid >> 7, h = gid & 127;
  if (n >= M) return;
  float acc = b1[h];
#pragma unroll
  for (int k = 0; k < K; ++k) acc += feat[n * K + k] * w1[k * 128 + h];
  out[n * 128 + h] = fb(acc > 0.f ? acc : 0.f);
}

// ---------------- MFMA GEMM, 64-row tile, K=128, Nout=128 ----------------
#define GM_NONE 0
#define GM_RELU 1
#define GM_LN 2

template <int MODE, bool DUAL>
__global__ __launch_bounds__(256, 2) void gemm64(
    const u16* __restrict__ A0, const u16* __restrict__ W0, const u16* __restrict__ A1,
    const u16* __restrict__ W1, const float* __restrict__ bias, const float* __restrict__ gg,
    const float* __restrict__ bb, const u16* __restrict__ resid, u16* __restrict__ out, int M) {
  __shared__ u16 sA[64][136];
  __shared__ u16 sW[128][136];
  const int tid = threadIdx.x;
  const int wave = tid >> 6, lane = tid & 63;
  const int q = lane >> 4, l16 = lane & 15;
  const int m0 = blockIdx.x * 64;

  f32x4_t acc[8];
#pragma unroll
  for (int b = 0; b < 8; ++b) acc[b] = (f32x4_t){0.f, 0.f, 0.f, 0.f};

  const int NKT = DUAL ? 2 : 1;
  for (int kt = 0; kt < NKT; ++kt) {
    const u16* A = (DUAL && kt) ? A1 : A0;
    const u16* W = (DUAL && kt) ? W1 : W0;
    if (kt) __syncthreads();
#pragma unroll
    for (int it = 0; it < 4; ++it) {  // A tile 64x128
      int lin = it * 256 + tid;
      int row = lin >> 4, ch = (lin & 15) * 8;
      uint4 v = make_uint4(0u, 0u, 0u, 0u);
      if (m0 + row < M) v = *(const uint4*)(A + (size_t)(m0 + row) * 128 + ch);
      *(uint4*)(&sA[row][ch]) = v;
    }
#pragma unroll
    for (int it = 0; it < 8; ++it) {  // W transposed: sW[n][k] = W[k][n]
      int lin = it * 256 + tid;
      int k = lin >> 4, nc = (lin & 15) * 8;
      uint4 v = *(const uint4*)(W + k * 128 + nc);
      u16 tmp[8];
      *(uint4*)tmp = v;
#pragma unroll
      for (int j = 0; j < 8; ++j) sW[nc + j][k] = tmp[j];
    }
    __syncthreads();
#pragma unroll
    for (int kk = 0; kk < 128; kk += 32) {
      bf16x8_t af = *(const bf16x8_t*)(&sA[wave * 16 + l16][kk + q * 8]);
#pragma unroll
      for (int nt = 0; nt < 8; ++nt) {
        bf16x8_t bfv = *(const bf16x8_t*)(&sW[nt * 16 + l16][kk + q * 8]);
        acc[nt] = __builtin_amdgcn_mfma_f32_16x16x32_bf16(af, bfv, acc[nt], 0, 0, 0);
      }
    }
  }

  // epilogue
  float bcol[8], gcol[8], becol[8];
  if (MODE != GM_NONE) {
#pragma unroll
    for (int nt = 0; nt < 8; ++nt) bcol[nt] = bias[nt * 16 + l16];
  }
  if (MODE == GM_LN) {
#pragma unroll
    for (int nt = 0; nt < 8; ++nt) {
      gcol[nt] = gg[nt * 16 + l16];
      becol[nt] = bb[nt * 16 + l16];
    }
  }
  const int rowb = wave * 16 + q * 4;
  if (MODE == GM_NONE) {
#pragma unroll
    for (int r = 0; r < 4; ++r) {
      int row = m0 + rowb + r;
      if (row < M) {
#pragma unroll
        for (int nt = 0; nt < 8; ++nt)
          out[(size_t)row * 128 + nt * 16 + l16] = fb(acc[nt][r]);
      }
    }
  } else if (MODE == GM_RELU) {
#pragma unroll
    for (int r = 0; r < 4; ++r) {
      int row = m0 + rowb + r;
      if (row < M) {
#pragma unroll
        for (int nt = 0; nt < 8; ++nt) {
          float v = acc[nt][r] + bcol[nt];
          out[(size_t)row * 128 + nt * 16 + l16] = fb(v > 0.f ? v : 0.f);
        }
      }
    }
  } else {
    float s[4] = {0, 0, 0, 0}, ss[4] = {0, 0, 0, 0};
#pragma unroll
    for (int r = 0; r < 4; ++r)
#pragma unroll
      for (int nt = 0; nt < 8; ++nt) {
        float v = acc[nt][r] + bcol[nt];
        s[r] += v;
        ss[r] += v * v;
      }
#pragma unroll
    for (int r = 0; r < 4; ++r) {
#pragma unroll
      for (int m = 1; m <= 8; m <<= 1) {
        s[r] += __shfl_xor(s[r], m, 64);
        ss[r] += __shfl_xor(ss[r], m, 64);
      }
    }
#pragma unroll
    for (int r = 0; r < 4; ++r) {
      int row = m0 + rowb + r;
      if (row >= M) continue;
      float mean = s[r] * (1.f / 128.f);
      float var = fmaxf(ss[r] * (1.f / 128.f) - mean * mean, 0.f);
      float rstd = rsqrtf(var + 1e-5f);
#pragma unroll
      for (int nt = 0; nt < 8; ++nt) {
        float v = (acc[nt][r] + bcol[nt] - mean) * rstd * gcol[nt] + becol[nt];
        if (resid) v += bl(resid[(size_t)row * 128 + nt * 16 + l16]);
        out[(size_t)row * 128 + nt * 16 + l16] = fb(v);
      }
    }
  }
}

// ---------------- fused edge kernel ----------------
// Per 64-edge tile:
//   T = eh_tile @ WC (MFMA); H = relu(T + gather(xhA,xhB) + b1) -> LDS
//   Y = LN(H @ W2 + b2); MSG: atomicAdd scat[recv] += Y; else eh += Y (residual)
template <bool MSG>
__global__ __launch_bounds__(256, 2) void gemm_edge(
    const u16* __restrict__ eh, const u16* __restrict__ xhA, const u16* __restrict__ xhB,
    const u16* __restrict__ WC, const float* __restrict__ b1, const u16* __restrict__ W2,
    const float* __restrict__ b2, const float* __restrict__ gg, const float* __restrict__ bb,
    const int* __restrict__ ei, u16* __restrict__ out, float* __restrict__ scat, int E) {
  __shared__ u16 sA[64][136];
  __shared__ u16 sW[128][136];
  const int tid = threadIdx.x;
  const int wave = tid >> 6, lane = tid & 63;
  const int q = lane >> 4, l16 = lane & 15;
  const int m0 = blockIdx.x * 64;
  const int rowb = wave * 16 + q * 4;

  // phase 0: stage eh tile + WC^T
#pragma unroll
  for (int it = 0; it < 4; ++it) {
    int lin = it * 256 + tid;
    int row = lin >> 4, ch = (lin & 15) * 8;
    uint4 v = make_uint4(0u, 0u, 0u, 0u);
    if (m0 + row < E) v = *(const uint4*)(eh + (size_t)(m0 + row) * 128 + ch);
    *(uint4*)(&sA[row][ch]) = v;
  }
#pragma unroll
  for (int it = 0; it < 8; ++it) {
    int lin = it * 256 + tid;
    int k = lin >> 4, nc = (lin & 15) * 8;
    uint4 v = *(const uint4*)(WC + k * 128 + nc);
    u16 tmp[8];
    *(uint4*)tmp = v;
#pragma unroll
    for (int j = 0; j < 8; ++j) sW[nc + j][k] = tmp[j];
  }
  __syncthreads();

  // phase 1: T = eh @ WC
  f32x4_t accC[8];
#pragma unroll
  for (int b = 0; b < 8; ++b) accC[b] = (f32x4_t){0.f, 0.f, 0.f, 0.f};
#pragma unroll
  for (int kk = 0; kk < 128; kk += 32) {
    bf16x8_t af = *(const bf16x8_t*)(&sA[wave * 16 + l16][kk + q * 8]);
#pragma unroll
    for (int nt = 0; nt < 8; ++nt) {
      bf16x8_t bfv = *(const bf16x8_t*)(&sW[nt * 16 + l16][kk + q * 8]);
      accC[nt] = __builtin_amdgcn_mfma_f32_16x16x32_bf16(af, bfv, accC[nt], 0, 0, 0);
    }
  }
  __syncthreads();  // sA/sW dead

  // phase 2: H = relu(T + gather + b1) into sA (C-layout ownership); restage sW <- W2^T
  float bcol1[8];
#pragma unroll
  for (int nt = 0; nt < 8; ++nt) bcol1[nt] = b1[nt * 16 + l16];
  int sidx[4], ridx[4];
#pragma unroll
  for (int r = 0; r < 4; ++r) {
    int e = m0 + rowb + r;
    sidx[r] = (e < E) ? ei[e] : 0;
    ridx[r] = (e < E) ? ei[E + e] : 0;
  }
#pragma unroll
  for (int r = 0; r < 4; ++r) {
    int e = m0 + rowb + r;
    bool ok = e < E;
    int ia = MSG ? ridx[r] : sidx[r];
    int ib = MSG ? sidx[r] : ridx[r];
#pragma unroll
    for (int nt = 0; nt < 8; ++nt) {
      int col = nt * 16 + l16;
      u16 hv = 0;
      if (ok) {
        float v = accC[nt][r] + bl(xhA[(size_t)ia * 128 + col]) +
                  bl(xhB[(size_t)ib * 128 + col]) + bcol1[nt];
        hv = fb(v > 0.f ? v : 0.f);
      }
      sA[rowb + r][col] = hv;
    }
  }
#pragma unroll
  for (int it = 0; it < 8; ++it) {
    int lin = it * 256 + tid;
    int k = lin >> 4, nc = (lin & 15) * 8;
    uint4 v = *(const uint4*)(W2 + k * 128 + nc);
    u16 tmp[8];
    *(uint4*)tmp = v;
#pragma unroll
    for (int j = 0; j < 8; ++j) sW[nc + j][k] = tmp[j];
  }
  __syncthreads();

  // phase 3: Y = H @ W2
  f32x4_t acc2[8];
#pragma unroll
  for (int b = 0; b < 8; ++b) acc2[b] = (f32x4_t){0.f, 0.f, 0.f, 0.f};
#pragma unroll
  for (int kk = 0; kk < 128; kk += 32) {
    bf16x8_t af = *(const bf16x8_t*)(&sA[wave * 16 + l16][kk + q * 8]);
#pragma unroll
    for (int nt = 0; nt < 8; ++nt) {
      bf16x8_t bfv = *(const bf16x8_t*)(&sW[nt * 16 + l16][kk + q * 8]);
      acc2[nt] = __builtin_amdgcn_mfma_f32_16x16x32_bf16(af, bfv, acc2[nt], 0, 0, 0);
    }
  }

  // phase 4: LN epilogue + scatter / residual write
  float bcol[8], gcol[8], becol[8];
#pragma unroll
  for (int nt = 0; nt < 8; ++nt) {
    bcol[nt] = b2[nt * 16 + l16];
    gcol[nt] = gg[nt * 16 + l16];
    becol[nt] = bb[nt * 16 + l16];
  }
  float s[4] = {0, 0, 0, 0}, ss[4] = {0, 0, 0, 0};
#pragma unroll
  for (int r = 0; r < 4; ++r)
#pragma unroll
    for (int nt = 0; nt < 8; ++nt) {
      float v = acc2[nt][r] + bcol[nt];
      s[r] += v;
      ss[r] += v * v;
    }
#pragma unroll
  for (int r = 0; r < 4; ++r) {
#pragma unroll
    for (int m = 1; m <= 8; m <<= 1) {
      s[r] += __shfl_xor(s[r], m, 64);
      ss[r] += __shfl_xor(ss[r], m, 64);
    }
  }
#pragma unroll
  for (int r = 0; r < 4; ++r) {
    int row = m0 + rowb + r;
    if (row >= E) continue;
    float mean = s[r] * (1.f / 128.f);
    float var = fmaxf(ss[r] * (1.f / 128.f) - mean * mean, 0.f);
    float rstd = rsqrtf(var + 1e-5f);
    if (MSG) {
      int rr = ridx[r];
#pragma unroll
      for (int nt = 0; nt < 8; ++nt) {
        float v = (acc2[nt][r] + bcol[nt] - mean) * rstd * gcol[nt] + becol[nt];
        atomicAdd(&scat[(size_t)rr * 128 + nt * 16 + l16], v);
      }
    } else {
#pragma unroll
      for (int nt = 0; nt < 8; ++nt) {
        size_t idx = (size_t)row * 128 + nt * 16 + l16;
        float v = (acc2[nt][r] + bcol[nt] - mean) * rstd * gcol[nt] + becol[nt];
        out[idx] = fb(v + bl(eh[idx]));
      }
    }
  }
}

__global__ void cvt_kernel(const float* __restrict__ in, u16* __restrict__ out, int count4) {
  int i = blockIdx.x * 256 + threadIdx.x;
  if (i >= count4) return;
  float4 v = *(const float4*)(in + (size_t)i * 4);
  u16 o[4] = {fb(v.x), fb(v.y), fb(v.z), fb(v.w)};
  *(uint2*)(out + (size_t)i * 4) = *(uint2*)o;
}

// decoder: wave per node, 128->64 swish -> 64->5, times dt; f32 weights + f32 out
__global__ void decoder_kernel(const u16* __restrict__ xh, const float* __restrict__ w1,
                               const float* __restrict__ b1, const float* __restrict__ w2,
                               const float* __restrict__ b2, float* __restrict__ out,
                               int n_nodes) {
  __shared__ float sx[4][128];
  int tid = threadIdx.x;
  int lw = tid >> 6, lane = tid & 63;
  int n0 = blockIdx.x * 4;
  for (int i = tid; i < 512; i += 256) {
    int nn = i >> 7, c = i & 127;
    int n = n0 + nn;
    sx[nn][c] = (n < n_nodes) ? bl(xh[(size_t)n * 128 + c]) : 0.f;
  }
  __syncthreads();
  int n = n0 + lw;
  float h = b1[lane];
#pragma unroll 16
  for (int k = 0; k < 128; ++k) h += sx[lw][k] * w1[k * 64 + lane];
  float hs = h * (1.f / (1.f + __expf(-h)));
  float d[5];
#pragma unroll
  for (int t = 0; t < 5; ++t) {
    float p = hs * w2[lane * 5 + t];
#pragma unroll
    for (int m = 1; m <= 32; m <<= 1) p += __shfl_xor(p, m, 64);
    d[t] = p;
  }
  if (lane == 0 && n < n_nodes) {
#pragma unroll
    for (int t = 0; t < 5; ++t)
      out[(size_t)n * 5 + t] = (float)(t + 1) * (d[t] + b2[t]);
  }
}

extern "C" void kernel_launch(void* const* d_in, const int* in_sizes, int n_in, void* d_out,
                              int out_size, void* d_ws, size_t ws_size, hipStream_t stream) {
  auto F = [&](int i) { return (const float*)d_in[i]; };
  const int* edge_index = (const int*)d_in[6];
  const int N_ = in_sizes[0];
  const int E_ = in_sizes[6] / 2;

  char* wsb = (char*)d_ws;
  size_t off = 0;
  auto alloc = [&](size_t bytes) -> char* {
    char* p = wsb + off;
    off += (bytes + 255) & ~(size_t)255;
    return p;
  };
  u16* xh = (u16*)alloc((size_t)N_ * 128 * 2);
  u16* xhA = (u16*)alloc((size_t)N_ * 128 * 2);
  u16* xhB = (u16*)alloc((size_t)N_ * 128 * 2);
  u16* h1n = (u16*)alloc((size_t)N_ * 128 * 2);
  float* aggr = (float*)alloc((size_t)N_ * 128 * 4);
  u16* ehP = (u16*)alloc((size_t)E_ * 128 * 2);
  float* nfeat = (float*)xhA;  // alias (consumed before xhA live)
  float* efeat = (float*)xhB;  // alias
  u16* aggrb = h1n;            // alias
  // bf16 copies of the six MFMA weights
  u16* wne2 = (u16*)alloc(128 * 128 * 2);
  u16* wee2 = (u16*)alloc(128 * 128 * 2);
  u16* wpe1 = (u16*)alloc((size_t)3 * 384 * 128 * 2);
  u16* wpe2 = (u16*)alloc((size_t)3 * 128 * 128 * 2);
  u16* wpn1 = (u16*)alloc((size_t)3 * 256 * 128 * 2);
  u16* wpn2 = (u16*)alloc((size_t)3 * 128 * 128 * 2);

  if (off > ws_size) {
    sentinel_kernel<<<(out_size + 255) / 256, 256, 0, stream>>>((float*)d_out, out_size);
    return;
  }

  const int tilesN = (N_ + 63) / 64;
  const int tilesE = (E_ + 63) / 64;
  dim3 blk(256);

  cvt_f2b<<<(16384 + 255) / 256, blk, 0, stream>>>(F(13), wne2, 16384);
  cvt_f2b<<<(16384 + 255) / 256, blk, 0, stream>>>(F(19), wee2, 16384);
  cvt_f2b<<<(147456 + 255) / 256, blk, 0, stream>>>(F(23), wpe1, 147456);
  cvt_f2b<<<(49152 + 255) / 256, blk, 0, stream>>>(F(25), wpe2, 49152);
  cvt_f2b<<<(98304 + 255) / 256, blk, 0, stream>>>(F(29), wpn1, 98304);
  cvt_f2b<<<(49152 + 255) / 256, blk, 0, stream>>>(F(31), wpn2, 49152);

  // ---- encode ----
  node_feat_kernel<<<(N_ + 255) / 256, blk, 0, stream>>>(F(0), F(1), F(2), F(3), F(4), F(7),
                                                         F(8), nfeat, N_);
  enc1_kernel<9><<<(N_ * 128 + 255) / 256, blk, 0, stream>>>(nfeat, F(11), F(12), h1n, N_);
  gemm64<GM_LN, false><<<tilesN, blk, 0, stream>>>(h1n, wne2, nullptr, nullptr, F(14), F(15),
                                                   F(16), nullptr, xh, N_);
  edge_feat_kernel<<<(E_ + 255) / 256, blk, 0, stream>>>(edge_index, F(5), F(0), F(9), F(10),
                                                         efeat, E_);
  enc1_kernel<4><<<(E_ * 128 + 255) / 256, blk, 0, stream>>>(efeat, F(17), F(18), ehP, E_);
  gemm64<GM_LN, false><<<tilesE, blk, 0, stream>>>(ehP, wee2, nullptr, nullptr, F(20), F(21),
                                                   F(22), nullptr, ehP, E_);  // in place

  // ---- process steps ----
  for (int i = 0; i < 3; ++i) {
    const u16* WA = wpe1 + (size_t)i * 384 * 128;
    const u16* WB = WA + 128 * 128;
    const u16* WC = WA + 2 * 128 * 128;
    const float* pb1 = F(24) + i * 128;
    const u16* pw2 = wpe2 + (size_t)i * 128 * 128;
    const float* pb2 = F(26) + i * 128;
    const float* pg = F(27) + i * 128;
    const float* pbe = F(28) + i * 128;
    const u16* nwA = wpn1 + (size_t)i * 256 * 128;
    const u16* nwB = nwA + 128 * 128;
    const float* nb1 = F(30) + i * 128;
    const u16* nw2 = wpn2 + (size_t)i * 128 * 128;
    const float* nb2 = F(32) + i * 128;
    const float* ng = F(33) + i * 128;
    const float* nbe = F(34) + i * 128;

    gemm64<GM_NONE, false><<<tilesN, blk, 0, stream>>>(xh, WA, nullptr, nullptr, nullptr,
                                                       nullptr, nullptr, nullptr, xhA, N_);
    gemm64<GM_NONE, false><<<tilesN, blk, 0, stream>>>(xh, WB, nullptr, nullptr, nullptr,
                                                       nullptr, nullptr, nullptr, xhB, N_);
    (void)hipMemsetAsync(aggr, 0, (size_t)N_ * 128 * 4, stream);
    gemm_edge<true><<<tilesE, blk, 0, stream>>>(ehP, xhA, xhB, WC, pb1, pw2, pb2, pg, pbe,
                                                edge_index, nullptr, aggr, E_);
    gemm_edge<false><<<tilesE, blk, 0, stream>>>(ehP, xhA, xhB, WC, pb1, pw2, pb2, pg, pbe,
                                                 edge_index, ehP, nullptr, E_);  // in place
    cvt_kernel<<<(N_ * 128 / 4 + 255) / 256, blk, 0, stream>>>(aggr, aggrb, N_ * 128 / 4);
    gemm64<GM_RELU, true><<<tilesN, blk, 0, stream>>>(aggrb, nwA, xh, nwB, nb1, nullptr,
                                                      nullptr, nullptr, h1n, N_);
    gemm64<GM_LN, false><<<tilesN, blk, 0, stream>>>(h1n, nw2, nullptr, nullptr, nb2, ng, nbe,
                                                     xh, xh, N_);  // in place resid
  }

  // ---- decode (f32 out) ----
  decoder_kernel<<<(N_ + 3) / 4, blk, 0, stream>>>(xh, F(35), F(36), F(37), F(38),
                                                   (float*)d_out, N_);
}

// Round 8
// 1618.203 us; speedup vs baseline: 1.1796x; 1.1796x over previous
//
#include <hip/hip_runtime.h>
#include <stdint.h>

typedef unsigned short u16;
typedef __attribute__((ext_vector_type(8))) short bf16x8_t;
typedef __attribute__((ext_vector_type(4))) float f32x4_t;

__device__ __forceinline__ float bl(u16 x) {
  union { unsigned u; float f; } c; c.u = ((unsigned)x) << 16; return c.f;
}
__device__ __forceinline__ u16 fb(float x) {
  union { float f; unsigned u; } c; c.f = x;
  unsigned r = c.u + 0x7fffu + ((c.u >> 16) & 1u);
  return (u16)(r >> 16);
}

__global__ void sentinel_kernel(float* out, int n) {
  int i = blockIdx.x * 256 + threadIdx.x;
  if (i < n) out[i] = 12345.f;
}

// ---------------- weight transpose: wT[n][k] = fb(W[k][n]), 128x128 blocks ----------------
struct TSeg { const float* src; u16* dst; };
struct TArgs { TSeg s[23]; };
__global__ void transpose_w(TArgs a) {
  const float* src = a.s[blockIdx.x].src;
  u16* dst = a.s[blockIdx.x].dst;
  for (int e = threadIdx.x; e < 16384; e += 256) {
    int n = e >> 7, k = e & 127;
    dst[e] = fb(src[k * 128 + n]);
  }
}

// ---------------- feature kernels ----------------
__global__ void node_feat_kernel(const float* __restrict__ t, const float* __restrict__ tp,
                                 const float* __restrict__ q, const float* __restrict__ qp,
                                 const float* __restrict__ qn, const float* __restrict__ nm,
                                 const float* __restrict__ ns, float* __restrict__ nfeat,
                                 int n_nodes) {
  int n = blockIdx.x * 256 + threadIdx.x;
  if (n >= n_nodes) return;
  float u = t[n];
  float x[9];
  x[0] = u; x[1] = u - tp[n];
  float hq = q[n];
  x[2] = hq; x[3] = hq - qp[n];
#pragma unroll
  for (int j = 0; j < 5; ++j) x[4 + j] = qn[n * 5 + j];
#pragma unroll
  for (int k = 0; k < 9; ++k) nfeat[n * 9 + k] = (x[k] - nm[k]) / ns[k];
}

__global__ void edge_feat_kernel(const int* __restrict__ ei, const float* __restrict__ mp,
                                 const float* __restrict__ u, const float* __restrict__ em,
                                 const float* __restrict__ es, float* __restrict__ efeat,
                                 int n_edges) {
  int e = blockIdx.x * 256 + threadIdx.x;
  if (e >= n_edges) return;
  int s = ei[e], r = ei[n_edges + e];
  float rx = mp[s * 2] - mp[r * 2];
  float ry = mp[s * 2 + 1] - mp[r * 2 + 1];
  float d = sqrtf(rx * rx + ry * ry);
  float rt = u[s] - u[r];
  float x[4] = {rx, ry, d, rt};
#pragma unroll
  for (int k = 0; k < 4; ++k) efeat[e * 4 + k] = (x[k] - em[k]) / es[k];
}

template <int K>
__global__ void enc1_kernel(const float* __restrict__ feat, const float* __restrict__ w1,
                            const float* __restrict__ b1, u16* __restrict__ out, int M) {
  int gid = blockIdx.x * 256 + threadIdx.x;
  int n = gid >> 7, h = gid & 127;
  if (n >= M) return;
  float acc = b1[h];
#pragma unroll
  for (int k = 0; k < K; ++k) acc += feat[n * K + k] * w1[k * 128 + h];
  out[n * 128 + h] = fb(acc > 0.f ? acc : 0.f);
}

// ---------------- LDS-free MFMA GEMM, 64-row tile, K=128, Nout=128 ----------------
// A row-major [M,128]; WT transposed [n][k]. Fragments read directly from global.
#define GM_NONE 0
#define GM_RELU 1
#define GM_LN 2

template <int MODE, bool DUAL, bool A0F32>
__global__ __launch_bounds__(256) void gemm64(
    const void* __restrict__ A0v, const u16* __restrict__ WT0, const u16* __restrict__ A1,
    const u16* __restrict__ WT1, const float* __restrict__ bias, const float* __restrict__ gg,
    const float* __restrict__ bb, const u16* __restrict__ resid, u16* __restrict__ out, int M) {
  const int tid = threadIdx.x;
  const int wave = tid >> 6, lane = tid & 63;
  const int q = lane >> 4, l16 = lane & 15;
  const int m0 = blockIdx.x * 64;
  int arow = m0 + wave * 16 + l16;
  if (arow >= M) arow = M - 1;

  f32x4_t acc[8];
#pragma unroll
  for (int b = 0; b < 8; ++b) acc[b] = (f32x4_t){0.f, 0.f, 0.f, 0.f};

  const int NKT = DUAL ? 2 : 1;
  for (int kt = 0; kt < NKT; ++kt) {
    const u16* WT = kt ? WT1 : WT0;
#pragma unroll 1
    for (int kk = 0; kk < 4; ++kk) {
      bf16x8_t af;
      if (A0F32 && kt == 0) {
        const float* ap = (const float*)A0v + (size_t)arow * 128 + kk * 32 + q * 8;
        union { u16 u[8]; bf16x8_t v; } cv;
#pragma unroll
        for (int j = 0; j < 8; ++j) cv.u[j] = fb(ap[j]);
        af = cv.v;
      } else {
        const u16* ap = (kt ? A1 : (const u16*)A0v) + (size_t)arow * 128 + kk * 32 + q * 8;
        af = *(const bf16x8_t*)ap;
      }
      const u16* wp = WT + kk * 32 + q * 8;
#pragma unroll
      for (int nt = 0; nt < 8; ++nt) {
        bf16x8_t bfv = *(const bf16x8_t*)(wp + (size_t)(nt * 16 + l16) * 128);
        acc[nt] = __builtin_amdgcn_mfma_f32_16x16x32_bf16(af, bfv, acc[nt], 0, 0, 0);
      }
    }
  }

  const int rowb = wave * 16 + q * 4;
  if (MODE == GM_NONE) {
#pragma unroll
    for (int r = 0; r < 4; ++r) {
      int row = m0 + rowb + r;
      if (row < M) {
#pragma unroll
        for (int nt = 0; nt < 8; ++nt)
          out[(size_t)row * 128 + nt * 16 + l16] = fb(acc[nt][r]);
      }
    }
  } else if (MODE == GM_RELU) {
    float bcol[8];
#pragma unroll
    for (int nt = 0; nt < 8; ++nt) bcol[nt] = bias[nt * 16 + l16];
#pragma unroll
    for (int r = 0; r < 4; ++r) {
      int row = m0 + rowb + r;
      if (row < M) {
#pragma unroll
        for (int nt = 0; nt < 8; ++nt) {
          float v = acc[nt][r] + bcol[nt];
          out[(size_t)row * 128 + nt * 16 + l16] = fb(v > 0.f ? v : 0.f);
        }
      }
    }
  } else {
    float bcol[8], gcol[8], becol[8];
#pragma unroll
    for (int nt = 0; nt < 8; ++nt) {
      bcol[nt] = bias[nt * 16 + l16];
      gcol[nt] = gg[nt * 16 + l16];
      becol[nt] = bb[nt * 16 + l16];
    }
    float s[4] = {0, 0, 0, 0}, ss[4] = {0, 0, 0, 0};
#pragma unroll
    for (int r = 0; r < 4; ++r)
#pragma unroll
      for (int nt = 0; nt < 8; ++nt) {
        float v = acc[nt][r] + bcol[nt];
        s[r] += v;
        ss[r] += v * v;
      }
#pragma unroll
    for (int r = 0; r < 4; ++r) {
#pragma unroll
      for (int m = 1; m <= 8; m <<= 1) {
        s[r] += __shfl_xor(s[r], m, 64);
        ss[r] += __shfl_xor(ss[r], m, 64);
      }
    }
#pragma unroll
    for (int r = 0; r < 4; ++r) {
      int row = m0 + rowb + r;
      if (row >= M) continue;
      float mean = s[r] * (1.f / 128.f);
      float var = fmaxf(ss[r] * (1.f / 128.f) - mean * mean, 0.f);
      float rstd = rsqrtf(var + 1e-5f);
#pragma unroll
      for (int nt = 0; nt < 8; ++nt) {
        float v = (acc[nt][r] + bcol[nt] - mean) * rstd * gcol[nt] + becol[nt];
        if (resid) v += bl(resid[(size_t)row * 128 + nt * 16 + l16]);
        out[(size_t)row * 128 + nt * 16 + l16] = fb(v);
      }
    }
  }
}

// dual-output GEMM: out0 = A@W0, out1 = A@W1 (A read once)
__global__ __launch_bounds__(256) void gemm64_2w(
    const u16* __restrict__ A, const u16* __restrict__ WT0, const u16* __restrict__ WT1,
    u16* __restrict__ out0, u16* __restrict__ out1, int M) {
  const int tid = threadIdx.x;
  const int wave = tid >> 6, lane = tid & 63;
  const int q = lane >> 4, l16 = lane & 15;
  const int m0 = blockIdx.x * 64;
  int arow = m0 + wave * 16 + l16;
  if (arow >= M) arow = M - 1;

  f32x4_t a0[8], a1[8];
#pragma unroll
  for (int b = 0; b < 8; ++b) {
    a0[b] = (f32x4_t){0.f, 0.f, 0.f, 0.f};
    a1[b] = (f32x4_t){0.f, 0.f, 0.f, 0.f};
  }
#pragma unroll 1
  for (int kk = 0; kk < 4; ++kk) {
    bf16x8_t af = *(const bf16x8_t*)(A + (size_t)arow * 128 + kk * 32 + q * 8);
#pragma unroll
    for (int nt = 0; nt < 8; ++nt) {
      bf16x8_t b0 = *(const bf16x8_t*)(WT0 + (size_t)(nt * 16 + l16) * 128 + kk * 32 + q * 8);
      bf16x8_t b1v = *(const bf16x8_t*)(WT1 + (size_t)(nt * 16 + l16) * 128 + kk * 32 + q * 8);
      a0[nt] = __builtin_amdgcn_mfma_f32_16x16x32_bf16(af, b0, a0[nt], 0, 0, 0);
      a1[nt] = __builtin_amdgcn_mfma_f32_16x16x32_bf16(af, b1v, a1[nt], 0, 0, 0);
    }
  }
  const int rowb = wave * 16 + q * 4;
#pragma unroll
  for (int r = 0; r < 4; ++r) {
    int row = m0 + rowb + r;
    if (row < M) {
#pragma unroll
      for (int nt = 0; nt < 8; ++nt) {
        out0[(size_t)row * 128 + nt * 16 + l16] = fb(a0[nt][r]);
        out1[(size_t)row * 128 + nt * 16 + l16] = fb(a1[nt][r]);
      }
    }
  }
}

// ---------------- fused edge kernel (msg + edge update in one pass) ----------------
// T = eh@WC (shared); H_msg = relu(T + xhA[r] + xhB[s] + b1); H_edge = relu(T + xhA[s] + xhB[r] + b1)
// Ym = LN(H_msg@W2 + b2) -> atomicAdd aggr[recv]; Ye = LN(H_edge@W2 + b2) + eh -> eh (in place)
__global__ __launch_bounds__(256) void edge_fused(
    u16* __restrict__ eh, const u16* __restrict__ xhA, const u16* __restrict__ xhB,
    const u16* __restrict__ wtC, const float* __restrict__ b1, const u16* __restrict__ wt2,
    const float* __restrict__ b2, const float* __restrict__ gg, const float* __restrict__ bb,
    const int* __restrict__ ei, float* __restrict__ scat, int E) {
  __shared__ u16 sHm[64][136];
  __shared__ u16 sHe[64][136];
  const int tid = threadIdx.x;
  const int wave = tid >> 6, lane = tid & 63;
  const int q = lane >> 4, l16 = lane & 15;
  const int m0 = blockIdx.x * 64;
  const int rowb = wave * 16 + q * 4;
  int arow = m0 + wave * 16 + l16;
  int arc = arow < E ? arow : E - 1;

  // phase 1: T = eh @ WC (direct-global fragments)
  f32x4_t accC[8];
#pragma unroll
  for (int b = 0; b < 8; ++b) accC[b] = (f32x4_t){0.f, 0.f, 0.f, 0.f};
#pragma unroll 1
  for (int kk = 0; kk < 4; ++kk) {
    bf16x8_t af = *(const bf16x8_t*)(eh + (size_t)arc * 128 + kk * 32 + q * 8);
#pragma unroll
    for (int nt = 0; nt < 8; ++nt) {
      bf16x8_t bfv = *(const bf16x8_t*)(wtC + (size_t)(nt * 16 + l16) * 128 + kk * 32 + q * 8);
      accC[nt] = __builtin_amdgcn_mfma_f32_16x16x32_bf16(af, bfv, accC[nt], 0, 0, 0);
    }
  }

  // phase 2: gathers + build both H matrices in LDS (C-layout ownership)
  int sidx[4], ridx[4];
  bool okr[4];
#pragma unroll
  for (int r = 0; r < 4; ++r) {
    int e = m0 + rowb + r;
    okr[r] = e < E;
    sidx[r] = okr[r] ? ei[e] : 0;
    ridx[r] = okr[r] ? ei[E + e] : 0;
  }
  float b1c[8];
#pragma unroll
  for (int nt = 0; nt < 8; ++nt) b1c[nt] = b1[nt * 16 + l16];
#pragma unroll
  for (int r = 0; r < 4; ++r) {
#pragma unroll
    for (int nt = 0; nt < 8; ++nt) {
      int col = nt * 16 + l16;
      u16 hm = 0, he = 0;
      if (okr[r]) {
        float xar = bl(xhA[(size_t)ridx[r] * 128 + col]);
        float xas = bl(xhA[(size_t)sidx[r] * 128 + col]);
        float xbr = bl(xhB[(size_t)ridx[r] * 128 + col]);
        float xbs = bl(xhB[(size_t)sidx[r] * 128 + col]);
        float t = accC[nt][r] + b1c[nt];
        float vm = t + xar + xbs;
        float ve = t + xas + xbr;
        hm = fb(vm > 0.f ? vm : 0.f);
        he = fb(ve > 0.f ? ve : 0.f);
      }
      sHm[rowb + r][col] = hm;
      sHe[rowb + r][col] = he;
    }
  }
  __syncthreads();

  float bcol[8], gcol[8], becol[8];
#pragma unroll
  for (int nt = 0; nt < 8; ++nt) {
    bcol[nt] = b2[nt * 16 + l16];
    gcol[nt] = gg[nt * 16 + l16];
    becol[nt] = bb[nt * 16 + l16];
  }

  // phase 3a: Ym = H_msg @ W2 -> LN -> atomic scatter
  {
    f32x4_t acc[8];
#pragma unroll
    for (int b = 0; b < 8; ++b) acc[b] = (f32x4_t){0.f, 0.f, 0.f, 0.f};
#pragma unroll 1
    for (int kk = 0; kk < 4; ++kk) {
      bf16x8_t af = *(const bf16x8_t*)(&sHm[wave * 16 + l16][kk * 32 + q * 8]);
#pragma unroll
      for (int nt = 0; nt < 8; ++nt) {
        bf16x8_t bfv = *(const bf16x8_t*)(wt2 + (size_t)(nt * 16 + l16) * 128 + kk * 32 + q * 8);
        acc[nt] = __builtin_amdgcn_mfma_f32_16x16x32_bf16(af, bfv, acc[nt], 0, 0, 0);
      }
    }
    float s[4] = {0, 0, 0, 0}, ss[4] = {0, 0, 0, 0};
#pragma unroll
    for (int r = 0; r < 4; ++r)
#pragma unroll
      for (int nt = 0; nt < 8; ++nt) {
        float v = acc[nt][r] + bcol[nt];
        s[r] += v;
        ss[r] += v * v;
      }
#pragma unroll
    for (int r = 0; r < 4; ++r) {
#pragma unroll
      for (int m = 1; m <= 8; m <<= 1) {
        s[r] += __shfl_xor(s[r], m, 64);
        ss[r] += __shfl_xor(ss[r], m, 64);
      }
    }
#pragma unroll
    for (int r = 0; r < 4; ++r) {
      if (!okr[r]) continue;
      float mean = s[r] * (1.f / 128.f);
      float var = fmaxf(ss[r] * (1.f / 128.f) - mean * mean, 0.f);
      float rstd = rsqrtf(var + 1e-5f);
#pragma unroll
      for (int nt = 0; nt < 8; ++nt) {
        float v = (acc[nt][r] + bcol[nt] - mean) * rstd * gcol[nt] + becol[nt];
        atomicAdd(&scat[(size_t)ridx[r] * 128 + nt * 16 + l16], v);
      }
    }
  }

  // phase 3b: Ye = H_edge @ W2 -> LN -> eh += (in place, block-exclusive rows)
  {
    f32x4_t acc[8];
#pragma unroll
    for (int b = 0; b < 8; ++b) acc[b] = (f32x4_t){0.f, 0.f, 0.f, 0.f};
#pragma unroll 1
    for (int kk = 0; kk < 4; ++kk) {
      bf16x8_t af = *(const bf16x8_t*)(&sHe[wave * 16 + l16][kk * 32 + q * 8]);
#pragma unroll
      for (int nt = 0; nt < 8; ++nt) {
        bf16x8_t bfv = *(const bf16x8_t*)(wt2 + (size_t)(nt * 16 + l16) * 128 + kk * 32 + q * 8);
        acc[nt] = __builtin_amdgcn_mfma_f32_16x16x32_bf16(af, bfv, acc[nt], 0, 0, 0);
      }
    }
    float s[4] = {0, 0, 0, 0}, ss[4] = {0, 0, 0, 0};
#pragma unroll
    for (int r = 0; r < 4; ++r)
#pragma unroll
      for (int nt = 0; nt < 8; ++nt) {
        float v = acc[nt][r] + bcol[nt];
        s[r] += v;
        ss[r] += v * v;
      }
#pragma unroll
    for (int r = 0; r < 4; ++r) {
#pragma unroll
      for (int m = 1; m <= 8; m <<= 1) {
        s[r] += __shfl_xor(s[r], m, 64);
        ss[r] += __shfl_xor(ss[r], m, 64);
      }
    }
#pragma unroll
    for (int r = 0; r < 4; ++r) {
      int row = m0 + rowb + r;
      if (row >= E) continue;
      float mean = s[r] * (1.f / 128.f);
      float var = fmaxf(ss[r] * (1.f / 128.f) - mean * mean, 0.f);
      float rstd = rsqrtf(var + 1e-5f);
#pragma unroll
      for (int nt = 0; nt < 8; ++nt) {
        size_t idx = (size_t)row * 128 + nt * 16 + l16;
        float v = (acc[nt][r] + bcol[nt] - mean) * rstd * gcol[nt] + becol[nt];
        eh[idx] = fb(v + bl(eh[idx]));
      }
    }
  }
}

// decoder: wave per node, 128->64 swish -> 64->5, times dt
__global__ void decoder_kernel(const u16* __restrict__ xh, const float* __restrict__ w1,
                               const float* __restrict__ b1, const float* __restrict__ w2,
                               const float* __restrict__ b2, float* __restrict__ out,
                               int n_nodes) {
  __shared__ float sx[4][128];
  int tid = threadIdx.x;
  int lw = tid >> 6, lane = tid & 63;
  int n0 = blockIdx.x * 4;
  for (int i = tid; i < 512; i += 256) {
    int nn = i >> 7, c = i & 127;
    int n = n0 + nn;
    sx[nn][c] = (n < n_nodes) ? bl(xh[(size_t)n * 128 + c]) : 0.f;
  }
  __syncthreads();
  int n = n0 + lw;
  float h = b1[lane];
#pragma unroll 16
  for (int k = 0; k < 128; ++k) h += sx[lw][k] * w1[k * 64 + lane];
  float hs = h * (1.f / (1.f + __expf(-h)));
  float d[5];
#pragma unroll
  for (int t = 0; t < 5; ++t) {
    float p = hs * w2[lane * 5 + t];
#pragma unroll
    for (int m = 1; m <= 32; m <<= 1) p += __shfl_xor(p, m, 64);
    d[t] = p;
  }
  if (lane == 0 && n < n_nodes) {
#pragma unroll
    for (int t = 0; t < 5; ++t)
      out[(size_t)n * 5 + t] = (float)(t + 1) * (d[t] + b2[t]);
  }
}

extern "C" void kernel_launch(void* const* d_in, const int* in_sizes, int n_in, void* d_out,
                              int out_size, void* d_ws, size_t ws_size, hipStream_t stream) {
  auto F = [&](int i) { return (const float*)d_in[i]; };
  const int* edge_index = (const int*)d_in[6];
  const int N_ = in_sizes[0];
  const int E_ = in_sizes[6] / 2;

  char* wsb = (char*)d_ws;
  size_t off = 0;
  auto alloc = [&](size_t bytes) -> char* {
    char* p = wsb + off;
    off += (bytes + 255) & ~(size_t)255;
    return p;
  };
  u16* xh = (u16*)alloc((size_t)N_ * 128 * 2);
  u16* xhA = (u16*)alloc((size_t)N_ * 128 * 2);
  u16* xhB = (u16*)alloc((size_t)N_ * 128 * 2);
  u16* h1n = (u16*)alloc((size_t)N_ * 128 * 2);
  float* aggr = (float*)alloc((size_t)N_ * 128 * 4);
  u16* ehP = (u16*)alloc((size_t)E_ * 128 * 2);
  float* nfeat = (float*)xhA;  // alias (consumed before xhA live)
  float* efeat = (float*)xhB;  // alias
  // transposed bf16 weights
  u16* wne2T = (u16*)alloc(16384 * 2);
  u16* wee2T = (u16*)alloc(16384 * 2);
  u16* wpe1T = (u16*)alloc((size_t)9 * 16384 * 2);   // [i][A,B,C]
  u16* wpe2T = (u16*)alloc((size_t)3 * 16384 * 2);
  u16* wpn1T = (u16*)alloc((size_t)6 * 16384 * 2);   // [i][A,B]
  u16* wpn2T = (u16*)alloc((size_t)3 * 16384 * 2);

  if (off > ws_size) {
    sentinel_kernel<<<(out_size + 255) / 256, 256, 0, stream>>>((float*)d_out, out_size);
    return;
  }

  TArgs ta;
  int ts = 0;
  ta.s[ts++] = {F(13), wne2T};
  ta.s[ts++] = {F(19), wee2T};
  for (int i = 0; i < 3; ++i)
    for (int b = 0; b < 3; ++b)
      ta.s[ts++] = {F(23) + (size_t)(i * 3 + b) * 16384, wpe1T + (size_t)(i * 3 + b) * 16384};
  for (int i = 0; i < 3; ++i) ta.s[ts++] = {F(25) + (size_t)i * 16384, wpe2T + (size_t)i * 16384};
  for (int i = 0; i < 3; ++i)
    for (int b = 0; b < 2; ++b)
      ta.s[ts++] = {F(29) + (size_t)(i * 2 + b) * 16384, wpn1T + (size_t)(i * 2 + b) * 16384};
  for (int i = 0; i < 3; ++i) ta.s[ts++] = {F(31) + (size_t)i * 16384, wpn2T + (size_t)i * 16384};

  const int tilesN = (N_ + 63) / 64;
  const int tilesE = (E_ + 63) / 64;
  dim3 blk(256);

  transpose_w<<<23, blk, 0, stream>>>(ta);

  // ---- encode ----
  node_feat_kernel<<<(N_ + 255) / 256, blk, 0, stream>>>(F(0), F(1), F(2), F(3), F(4), F(7),
                                                         F(8), nfeat, N_);
  enc1_kernel<9><<<(N_ * 128 + 255) / 256, blk, 0, stream>>>(nfeat, F(11), F(12), h1n, N_);
  gemm64<GM_LN, false, false><<<tilesN, blk, 0, stream>>>(h1n, wne2T, nullptr, nullptr, F(14),
                                                          F(15), F(16), nullptr, xh, N_);
  edge_feat_kernel<<<(E_ + 255) / 256, blk, 0, stream>>>(edge_index, F(5), F(0), F(9), F(10),
                                                         efeat, E_);
  enc1_kernel<4><<<(E_ * 128 + 255) / 256, blk, 0, stream>>>(efeat, F(17), F(18), ehP, E_);
  gemm64<GM_LN, false, false><<<tilesE, blk, 0, stream>>>(ehP, wee2T, nullptr, nullptr, F(20),
                                                          F(21), F(22), nullptr, ehP, E_);

  // ---- process steps ----
  for (int i = 0; i < 3; ++i) {
    const u16* wtA = wpe1T + (size_t)(i * 3 + 0) * 16384;
    const u16* wtB = wpe1T + (size_t)(i * 3 + 1) * 16384;
    const u16* wtC = wpe1T + (size_t)(i * 3 + 2) * 16384;
    const float* pb1 = F(24) + i * 128;
    const u16* wt2 = wpe2T + (size_t)i * 16384;
    const float* pb2 = F(26) + i * 128;
    const float* pg = F(27) + i * 128;
    const float* pbe = F(28) + i * 128;
    const u16* wtnA = wpn1T + (size_t)(i * 2 + 0) * 16384;
    const u16* wtnB = wpn1T + (size_t)(i * 2 + 1) * 16384;
    const float* nb1 = F(30) + i * 128;
    const u16* wtn2 = wpn2T + (size_t)i * 16384;
    const float* nb2 = F(32) + i * 128;
    const float* ng = F(33) + i * 128;
    const float* nbe = F(34) + i * 128;

    gemm64_2w<<<tilesN, blk, 0, stream>>>(xh, wtA, wtB, xhA, xhB, N_);
    (void)hipMemsetAsync(aggr, 0, (size_t)N_ * 128 * 4, stream);
    edge_fused<<<tilesE, blk, 0, stream>>>(ehP, xhA, xhB, wtC, pb1, wt2, pb2, pg, pbe,
                                           edge_index, aggr, E_);
    gemm64<GM_RELU, true, true><<<tilesN, blk, 0, stream>>>(aggr, wtnA, xh, wtnB, nb1, nullptr,
                                                            nullptr, nullptr, h1n, N_);
    gemm64<GM_LN, false, false><<<tilesN, blk, 0, stream>>>(h1n, wtn2, nullptr, nullptr, nb2,
                                                            ng, nbe, xh, xh, N_);
  }

  // ---- decode ----
  decoder_kernel<<<(N_ + 3) / 4, blk, 0, stream>>>(xh, F(35), F(36), F(37), F(38),
                                                   (float*)d_out, N_);
}

// Round 9
// 1513.526 us; speedup vs baseline: 1.2612x; 1.0692x over previous
//
#include <hip/hip_runtime.h>
#include <stdint.h>

typedef unsigned short u16;
typedef __attribute__((ext_vector_type(8))) short bf16x8_t;
typedef __attribute__((ext_vector_type(4))) float f32x4_t;

__device__ __forceinline__ float bl(u16 x) {
  union { unsigned u; float f; } c; c.u = ((unsigned)x) << 16; return c.f;
}
__device__ __forceinline__ u16 fb(float x) {
  union { float f; unsigned u; } c; c.f = x;
  unsigned r = c.u + 0x7fffu + ((c.u >> 16) & 1u);
  return (u16)(r >> 16);
}

__global__ void sentinel_kernel(float* out, int n) {
  int i = blockIdx.x * 256 + threadIdx.x;
  if (i < n) out[i] = 12345.f;
}

// ---------------- weight transpose: wT[n][k] = fb(W[k][n]) ----------------
struct TSeg { const float* src; u16* dst; };
struct TArgs { TSeg s[23]; };
__global__ void transpose_w(TArgs a) {
  const float* src = a.s[blockIdx.x].src;
  u16* dst = a.s[blockIdx.x].dst;
  for (int e = threadIdx.x; e < 16384; e += 256) {
    int n = e >> 7, k = e & 127;
    dst[e] = fb(src[k * 128 + n]);
  }
}

// ---------------- feature kernels ----------------
__global__ void node_feat_kernel(const float* __restrict__ t, const float* __restrict__ tp,
                                 const float* __restrict__ q, const float* __restrict__ qp,
                                 const float* __restrict__ qn, const float* __restrict__ nm,
                                 const float* __restrict__ ns, float* __restrict__ nfeat,
                                 int n_nodes) {
  int n = blockIdx.x * 256 + threadIdx.x;
  if (n >= n_nodes) return;
  float u = t[n];
  float x[9];
  x[0] = u; x[1] = u - tp[n];
  float hq = q[n];
  x[2] = hq; x[3] = hq - qp[n];
#pragma unroll
  for (int j = 0; j < 5; ++j) x[4 + j] = qn[n * 5 + j];
#pragma unroll
  for (int k = 0; k < 9; ++k) nfeat[n * 9 + k] = (x[k] - nm[k]) / ns[k];
}

__global__ void edge_feat_kernel(const int* __restrict__ ei, const float* __restrict__ mp,
                                 const float* __restrict__ u, const float* __restrict__ em,
                                 const float* __restrict__ es, float* __restrict__ efeat,
                                 int n_edges) {
  int e = blockIdx.x * 256 + threadIdx.x;
  if (e >= n_edges) return;
  int s = ei[e], r = ei[n_edges + e];
  float rx = mp[s * 2] - mp[r * 2];
  float ry = mp[s * 2 + 1] - mp[r * 2 + 1];
  float d = sqrtf(rx * rx + ry * ry);
  float rt = u[s] - u[r];
  float x[4] = {rx, ry, d, rt};
#pragma unroll
  for (int k = 0; k < 4; ++k) efeat[e * 4 + k] = (x[k] - em[k]) / es[k];
}

template <int K>
__global__ void enc1_kernel(const float* __restrict__ feat, const float* __restrict__ w1,
                            const float* __restrict__ b1, u16* __restrict__ out, int M) {
  int gid = blockIdx.x * 256 + threadIdx.x;
  int n = gid >> 7, h = gid & 127;
  if (n >= M) return;
  float acc = b1[h];
#pragma unroll
  for (int k = 0; k < K; ++k) acc += feat[n * K + k] * w1[k * 128 + h];
  out[n * 128 + h] = fb(acc > 0.f ? acc : 0.f);
}

// ---------------- LDS-free-GEMM + LDS-staged vector-store epilogue ----------------
#define GM_NONE 0
#define GM_RELU 1
#define GM_LN 2

template <int MODE, bool DUAL, bool A0F32>
__global__ __launch_bounds__(256) void gemm64(
    const void* __restrict__ A0v, const u16* __restrict__ WT0, const u16* __restrict__ A1,
    const u16* __restrict__ WT1, const float* __restrict__ bias, const float* __restrict__ gg,
    const float* __restrict__ bb, const u16* __restrict__ resid, u16* __restrict__ out, int M) {
  __shared__ u16 sO[64][136];
  const int tid = threadIdx.x;
  const int wave = tid >> 6, lane = tid & 63;
  const int q = lane >> 4, l16 = lane & 15;
  const int m0 = blockIdx.x * 64;
  int arow = m0 + wave * 16 + l16;
  if (arow >= M) arow = M - 1;

  f32x4_t acc[8];
#pragma unroll
  for (int b = 0; b < 8; ++b) acc[b] = (f32x4_t){0.f, 0.f, 0.f, 0.f};

  const int NKT = DUAL ? 2 : 1;
  for (int kt = 0; kt < NKT; ++kt) {
    const u16* WT = kt ? WT1 : WT0;
#pragma unroll 1
    for (int kk = 0; kk < 4; ++kk) {
      bf16x8_t af;
      if (A0F32 && kt == 0) {
        const float* ap = (const float*)A0v + (size_t)arow * 128 + kk * 32 + q * 8;
        union { u16 u[8]; bf16x8_t v; } cv;
#pragma unroll
        for (int j = 0; j < 8; ++j) cv.u[j] = fb(ap[j]);
        af = cv.v;
      } else {
        const u16* ap = (kt ? A1 : (const u16*)A0v) + (size_t)arow * 128 + kk * 32 + q * 8;
        af = *(const bf16x8_t*)ap;
      }
      const u16* wp = WT + kk * 32 + q * 8;
#pragma unroll
      for (int nt = 0; nt < 8; ++nt) {
        bf16x8_t bfv = *(const bf16x8_t*)(wp + (size_t)(nt * 16 + l16) * 128);
        acc[nt] = __builtin_amdgcn_mfma_f32_16x16x32_bf16(af, bfv, acc[nt], 0, 0, 0);
      }
    }
  }

  const int rowb = wave * 16 + q * 4;
  if (MODE == GM_NONE) {
#pragma unroll
    for (int r = 0; r < 4; ++r)
#pragma unroll
      for (int nt = 0; nt < 8; ++nt) sO[rowb + r][nt * 16 + l16] = fb(acc[nt][r]);
  } else if (MODE == GM_RELU) {
    float bcol[8];
#pragma unroll
    for (int nt = 0; nt < 8; ++nt) bcol[nt] = bias[nt * 16 + l16];
#pragma unroll
    for (int r = 0; r < 4; ++r)
#pragma unroll
      for (int nt = 0; nt < 8; ++nt) {
        float v = acc[nt][r] + bcol[nt];
        sO[rowb + r][nt * 16 + l16] = fb(v > 0.f ? v : 0.f);
      }
  } else {
    float bcol[8], gcol[8], becol[8];
#pragma unroll
    for (int nt = 0; nt < 8; ++nt) {
      bcol[nt] = bias[nt * 16 + l16];
      gcol[nt] = gg[nt * 16 + l16];
      becol[nt] = bb[nt * 16 + l16];
    }
    float s[4] = {0, 0, 0, 0}, ss[4] = {0, 0, 0, 0};
#pragma unroll
    for (int r = 0; r < 4; ++r)
#pragma unroll
      for (int nt = 0; nt < 8; ++nt) {
        float v = acc[nt][r] + bcol[nt];
        s[r] += v;
        ss[r] += v * v;
      }
#pragma unroll
    for (int r = 0; r < 4; ++r) {
#pragma unroll
      for (int m = 1; m <= 8; m <<= 1) {
        s[r] += __shfl_xor(s[r], m, 64);
        ss[r] += __shfl_xor(ss[r], m, 64);
      }
    }
#pragma unroll
    for (int r = 0; r < 4; ++r) {
      float mean = s[r] * (1.f / 128.f);
      float var = fmaxf(ss[r] * (1.f / 128.f) - mean * mean, 0.f);
      float rstd = rsqrtf(var + 1e-5f);
#pragma unroll
      for (int nt = 0; nt < 8; ++nt) {
        float v = (acc[nt][r] + bcol[nt] - mean) * rstd * gcol[nt] + becol[nt];
        sO[rowb + r][nt * 16 + l16] = fb(v);
      }
    }
  }
  __syncthreads();
  // row-wise vector store (+ residual)
#pragma unroll
  for (int it = 0; it < 4; ++it) {
    int lin = it * 256 + tid;
    int row = lin >> 4, ch = (lin & 15) * 8;
    int grow = m0 + row;
    if (grow >= M) continue;
    u16 o8[8];
    *(uint4*)o8 = *(uint4*)(&sO[row][ch]);
    if (MODE == GM_LN && resid) {
      u16 r8[8];
      *(uint4*)r8 = *(const uint4*)(resid + (size_t)grow * 128 + ch);
#pragma unroll
      for (int j = 0; j < 8; ++j) o8[j] = fb(bl(o8[j]) + bl(r8[j]));
    }
    *(uint4*)(out + (size_t)grow * 128 + ch) = *(uint4*)o8;
  }
}

// dual-output GEMM: out0 = A@W0, out1 = A@W1 (A read once)
__global__ __launch_bounds__(256) void gemm64_2w(
    const u16* __restrict__ A, const u16* __restrict__ WT0, const u16* __restrict__ WT1,
    u16* __restrict__ out0, u16* __restrict__ out1, int M) {
  __shared__ u16 sO0[64][136];
  __shared__ u16 sO1[64][136];
  const int tid = threadIdx.x;
  const int wave = tid >> 6, lane = tid & 63;
  const int q = lane >> 4, l16 = lane & 15;
  const int m0 = blockIdx.x * 64;
  int arow = m0 + wave * 16 + l16;
  if (arow >= M) arow = M - 1;

  f32x4_t a0[8], a1[8];
#pragma unroll
  for (int b = 0; b < 8; ++b) {
    a0[b] = (f32x4_t){0.f, 0.f, 0.f, 0.f};
    a1[b] = (f32x4_t){0.f, 0.f, 0.f, 0.f};
  }
#pragma unroll 1
  for (int kk = 0; kk < 4; ++kk) {
    bf16x8_t af = *(const bf16x8_t*)(A + (size_t)arow * 128 + kk * 32 + q * 8);
#pragma unroll
    for (int nt = 0; nt < 8; ++nt) {
      bf16x8_t b0 = *(const bf16x8_t*)(WT0 + (size_t)(nt * 16 + l16) * 128 + kk * 32 + q * 8);
      bf16x8_t b1v = *(const bf16x8_t*)(WT1 + (size_t)(nt * 16 + l16) * 128 + kk * 32 + q * 8);
      a0[nt] = __builtin_amdgcn_mfma_f32_16x16x32_bf16(af, b0, a0[nt], 0, 0, 0);
      a1[nt] = __builtin_amdgcn_mfma_f32_16x16x32_bf16(af, b1v, a1[nt], 0, 0, 0);
    }
  }
  const int rowb = wave * 16 + q * 4;
#pragma unroll
  for (int r = 0; r < 4; ++r)
#pragma unroll
    for (int nt = 0; nt < 8; ++nt) {
      sO0[rowb + r][nt * 16 + l16] = fb(a0[nt][r]);
      sO1[rowb + r][nt * 16 + l16] = fb(a1[nt][r]);
    }
  __syncthreads();
#pragma unroll
  for (int it = 0; it < 4; ++it) {
    int lin = it * 256 + tid;
    int row = lin >> 4, ch = (lin & 15) * 8;
    int grow = m0 + row;
    if (grow >= M) continue;
    *(uint4*)(out0 + (size_t)grow * 128 + ch) = *(uint4*)(&sO0[row][ch]);
    *(uint4*)(out1 + (size_t)grow * 128 + ch) = *(uint4*)(&sO1[row][ch]);
  }
}

// ---------------- fused edge kernel (vectorized gathers) ----------------
__global__ __launch_bounds__(256) void edge_fused(
    u16* __restrict__ eh, const u16* __restrict__ xhA, const u16* __restrict__ xhB,
    const u16* __restrict__ wtC, const float* __restrict__ b1, const u16* __restrict__ wt2,
    const float* __restrict__ b2, const float* __restrict__ gg, const float* __restrict__ bb,
    const int* __restrict__ ei, float* __restrict__ scat, int E) {
  __shared__ u16 sHm[64][136];
  __shared__ u16 sHe[64][136];
  __shared__ int sS[64], sR[64];
  const int tid = threadIdx.x;
  const int wave = tid >> 6, lane = tid & 63;
  const int q = lane >> 4, l16 = lane & 15;
  const int m0 = blockIdx.x * 64;
  const int rowb = wave * 16 + q * 4;
  int arow = m0 + wave * 16 + l16;
  int arc = arow < E ? arow : E - 1;

  if (tid < 64) {
    int e = m0 + tid;
    sS[tid] = (e < E) ? ei[e] : 0;
    sR[tid] = (e < E) ? ei[E + e] : 0;
  }

  // phase 1: T = eh @ WC (direct-global fragments)
  f32x4_t accC[8];
#pragma unroll
  for (int b = 0; b < 8; ++b) accC[b] = (f32x4_t){0.f, 0.f, 0.f, 0.f};
#pragma unroll 1
  for (int kk = 0; kk < 4; ++kk) {
    bf16x8_t af = *(const bf16x8_t*)(eh + (size_t)arc * 128 + kk * 32 + q * 8);
#pragma unroll
    for (int nt = 0; nt < 8; ++nt) {
      bf16x8_t bfv = *(const bf16x8_t*)(wtC + (size_t)(nt * 16 + l16) * 128 + kk * 32 + q * 8);
      accC[nt] = __builtin_amdgcn_mfma_f32_16x16x32_bf16(af, bfv, accC[nt], 0, 0, 0);
    }
  }
  // phase 2a: write T (bf16) into sHm, C-layout
#pragma unroll
  for (int r = 0; r < 4; ++r)
#pragma unroll
    for (int nt = 0; nt < 8; ++nt) sHm[rowb + r][nt * 16 + l16] = fb(accC[nt][r]);
  __syncthreads();

  // phase 2b: row-wise vectorized gather + ReLU; sHm <- H_msg, sHe <- H_edge
#pragma unroll
  for (int it = 0; it < 4; ++it) {
    int lin = it * 256 + tid;
    int row = lin >> 4, ch = (lin & 15) * 8;
    bool ok = (m0 + row) < E;
    int s_ = sS[row], r_ = sR[row];
    u16 t8[8], ar[8], as_[8], br[8], bs[8], hm[8], he[8];
    *(uint4*)t8 = *(uint4*)(&sHm[row][ch]);
    *(uint4*)ar = *(const uint4*)(xhA + (size_t)r_ * 128 + ch);
    *(uint4*)as_ = *(const uint4*)(xhA + (size_t)s_ * 128 + ch);
    *(uint4*)br = *(const uint4*)(xhB + (size_t)r_ * 128 + ch);
    *(uint4*)bs = *(const uint4*)(xhB + (size_t)s_ * 128 + ch);
#pragma unroll
    for (int j = 0; j < 8; ++j) {
      float t = bl(t8[j]) + b1[ch + j];
      float vm = t + bl(ar[j]) + bl(bs[j]);
      float ve = t + bl(as_[j]) + bl(br[j]);
      hm[j] = (ok && vm > 0.f) ? fb(vm) : 0;
      he[j] = (ok && ve > 0.f) ? fb(ve) : 0;
    }
    *(uint4*)(&sHm[row][ch]) = *(uint4*)hm;
    *(uint4*)(&sHe[row][ch]) = *(uint4*)he;
  }
  __syncthreads();

  float bcol[8], gcol[8], becol[8];
#pragma unroll
  for (int nt = 0; nt < 8; ++nt) {
    bcol[nt] = b2[nt * 16 + l16];
    gcol[nt] = gg[nt * 16 + l16];
    becol[nt] = bb[nt * 16 + l16];
  }

  // phase 3a: Ym = H_msg @ W2 -> LN -> atomic scatter (C-layout, 64B/quad coalesced)
  {
    f32x4_t acc[8];
#pragma unroll
    for (int b = 0; b < 8; ++b) acc[b] = (f32x4_t){0.f, 0.f, 0.f, 0.f};
#pragma unroll 1
    for (int kk = 0; kk < 4; ++kk) {
      bf16x8_t af = *(const bf16x8_t*)(&sHm[wave * 16 + l16][kk * 32 + q * 8]);
#pragma unroll
      for (int nt = 0; nt < 8; ++nt) {
        bf16x8_t bfv = *(const bf16x8_t*)(wt2 + (size_t)(nt * 16 + l16) * 128 + kk * 32 + q * 8);
        acc[nt] = __builtin_amdgcn_mfma_f32_16x16x32_bf16(af, bfv, acc[nt], 0, 0, 0);
      }
    }
    float s[4] = {0, 0, 0, 0}, ss[4] = {0, 0, 0, 0};
#pragma unroll
    for (int r = 0; r < 4; ++r)
#pragma unroll
      for (int nt = 0; nt < 8; ++nt) {
        float v = acc[nt][r] + bcol[nt];
        s[r] += v;
        ss[r] += v * v;
      }
#pragma unroll
    for (int r = 0; r < 4; ++r) {
#pragma unroll
      for (int m = 1; m <= 8; m <<= 1) {
        s[r] += __shfl_xor(s[r], m, 64);
        ss[r] += __shfl_xor(ss[r], m, 64);
      }
    }
#pragma unroll
    for (int r = 0; r < 4; ++r) {
      int row = m0 + rowb + r;
      if (row >= E) continue;
      int rr = sR[rowb + r];
      float mean = s[r] * (1.f / 128.f);
      float var = fmaxf(ss[r] * (1.f / 128.f) - mean * mean, 0.f);
      float rstd = rsqrtf(var + 1e-5f);
#pragma unroll
      for (int nt = 0; nt < 8; ++nt) {
        float v = (acc[nt][r] + bcol[nt] - mean) * rstd * gcol[nt] + becol[nt];
        atomicAdd(&scat[(size_t)rr * 128 + nt * 16 + l16], v);
      }
    }
  }

  // phase 3b: Ye = H_edge @ W2 -> LN -> stage to LDS -> row-wise residual+store
  f32x4_t acc[8];
#pragma unroll
  for (int b = 0; b < 8; ++b) acc[b] = (f32x4_t){0.f, 0.f, 0.f, 0.f};
#pragma unroll 1
  for (int kk = 0; kk < 4; ++kk) {
    bf16x8_t af = *(const bf16x8_t*)(&sHe[wave * 16 + l16][kk * 32 + q * 8]);
#pragma unroll
    for (int nt = 0; nt < 8; ++nt) {
      bf16x8_t bfv = *(const bf16x8_t*)(wt2 + (size_t)(nt * 16 + l16) * 128 + kk * 32 + q * 8);
      acc[nt] = __builtin_amdgcn_mfma_f32_16x16x32_bf16(af, bfv, acc[nt], 0, 0, 0);
    }
  }
  {
    float s[4] = {0, 0, 0, 0}, ss[4] = {0, 0, 0, 0};
#pragma unroll
    for (int r = 0; r < 4; ++r)
#pragma unroll
      for (int nt = 0; nt < 8; ++nt) {
        float v = acc[nt][r] + bcol[nt];
        s[r] += v;
        ss[r] += v * v;
      }
#pragma unroll
    for (int r = 0; r < 4; ++r) {
#pragma unroll
      for (int m = 1; m <= 8; m <<= 1) {
        s[r] += __shfl_xor(s[r], m, 64);
        ss[r] += __shfl_xor(ss[r], m, 64);
      }
    }
    __syncthreads();  // all LDS reads of sHm/sHe complete
#pragma unroll
    for (int r = 0; r < 4; ++r) {
      float mean = s[r] * (1.f / 128.f);
      float var = fmaxf(ss[r] * (1.f / 128.f) - mean * mean, 0.f);
      float rstd = rsqrtf(var + 1e-5f);
#pragma unroll
      for (int nt = 0; nt < 8; ++nt) {
        float v = (acc[nt][r] + bcol[nt] - mean) * rstd * gcol[nt] + becol[nt];
        sHm[rowb + r][nt * 16 + l16] = fb(v);
      }
    }
  }
  __syncthreads();
#pragma unroll
  for (int it = 0; it < 4; ++it) {
    int lin = it * 256 + tid;
    int row = lin >> 4, ch = (lin & 15) * 8;
    int grow = m0 + row;
    if (grow >= E) continue;
    u16 y8[8], e8[8];
    *(uint4*)y8 = *(uint4*)(&sHm[row][ch]);
    *(uint4*)e8 = *(const uint4*)(eh + (size_t)grow * 128 + ch);
#pragma unroll
    for (int j = 0; j < 8; ++j) y8[j] = fb(bl(y8[j]) + bl(e8[j]));
    *(uint4*)(eh + (size_t)grow * 128 + ch) = *(uint4*)y8;
  }
}

// decoder: wave per node, 128->64 swish -> 64->5, times dt
__global__ void decoder_kernel(const u16* __restrict__ xh, const float* __restrict__ w1,
                               const float* __restrict__ b1, const float* __restrict__ w2,
                               const float* __restrict__ b2, float* __restrict__ out,
                               int n_nodes) {
  __shared__ float sx[4][128];
  int tid = threadIdx.x;
  int lw = tid >> 6, lane = tid & 63;
  int n0 = blockIdx.x * 4;
  for (int i = tid; i < 512; i += 256) {
    int nn = i >> 7, c = i & 127;
    int n = n0 + nn;
    sx[nn][c] = (n < n_nodes) ? bl(xh[(size_t)n * 128 + c]) : 0.f;
  }
  __syncthreads();
  int n = n0 + lw;
  float h = b1[lane];
#pragma unroll 16
  for (int k = 0; k < 128; ++k) h += sx[lw][k] * w1[k * 64 + lane];
  float hs = h * (1.f / (1.f + __expf(-h)));
  float d[5];
#pragma unroll
  for (int t = 0; t < 5; ++t) {
    float p = hs * w2[lane * 5 + t];
#pragma unroll
    for (int m = 1; m <= 32; m <<= 1) p += __shfl_xor(p, m, 64);
    d[t] = p;
  }
  if (lane == 0 && n < n_nodes) {
#pragma unroll
    for (int t = 0; t < 5; ++t)
      out[(size_t)n * 5 + t] = (float)(t + 1) * (d[t] + b2[t]);
  }
}

extern "C" void kernel_launch(void* const* d_in, const int* in_sizes, int n_in, void* d_out,
                              int out_size, void* d_ws, size_t ws_size, hipStream_t stream) {
  auto F = [&](int i) { return (const float*)d_in[i]; };
  const int* edge_index = (const int*)d_in[6];
  const int N_ = in_sizes[0];
  const int E_ = in_sizes[6] / 2;

  char* wsb = (char*)d_ws;
  size_t off = 0;
  auto alloc = [&](size_t bytes) -> char* {
    char* p = wsb + off;
    off += (bytes + 255) & ~(size_t)255;
    return p;
  };
  u16* xh = (u16*)alloc((size_t)N_ * 128 * 2);
  u16* xhA = (u16*)alloc((size_t)N_ * 128 * 2);
  u16* xhB = (u16*)alloc((size_t)N_ * 128 * 2);
  u16* h1n = (u16*)alloc((size_t)N_ * 128 * 2);
  float* aggr = (float*)alloc((size_t)N_ * 128 * 4);
  u16* ehP = (u16*)alloc((size_t)E_ * 128 * 2);
  float* nfeat = (float*)xhA;  // alias (consumed before xhA live)
  float* efeat = (float*)xhB;  // alias
  u16* wne2T = (u16*)alloc(16384 * 2);
  u16* wee2T = (u16*)alloc(16384 * 2);
  u16* wpe1T = (u16*)alloc((size_t)9 * 16384 * 2);
  u16* wpe2T = (u16*)alloc((size_t)3 * 16384 * 2);
  u16* wpn1T = (u16*)alloc((size_t)6 * 16384 * 2);
  u16* wpn2T = (u16*)alloc((size_t)3 * 16384 * 2);

  if (off > ws_size) {
    sentinel_kernel<<<(out_size + 255) / 256, 256, 0, stream>>>((float*)d_out, out_size);
    return;
  }

  TArgs ta;
  int ts = 0;
  ta.s[ts++] = {F(13), wne2T};
  ta.s[ts++] = {F(19), wee2T};
  for (int i = 0; i < 3; ++i)
    for (int b = 0; b < 3; ++b)
      ta.s[ts++] = {F(23) + (size_t)(i * 3 + b) * 16384, wpe1T + (size_t)(i * 3 + b) * 16384};
  for (int i = 0; i < 3; ++i) ta.s[ts++] = {F(25) + (size_t)i * 16384, wpe2T + (size_t)i * 16384};
  for (int i = 0; i < 3; ++i)
    for (int b = 0; b < 2; ++b)
      ta.s[ts++] = {F(29) + (size_t)(i * 2 + b) * 16384, wpn1T + (size_t)(i * 2 + b) * 16384};
  for (int i = 0; i < 3; ++i) ta.s[ts++] = {F(31) + (size_t)i * 16384, wpn2T + (size_t)i * 16384};

  const int tilesN = (N_ + 63) / 64;
  const int tilesE = (E_ + 63) / 64;
  dim3 blk(256);

  transpose_w<<<23, blk, 0, stream>>>(ta);

  // ---- encode ----
  node_feat_kernel<<<(N_ + 255) / 256, blk, 0, stream>>>(F(0), F(1), F(2), F(3), F(4), F(7),
                                                         F(8), nfeat, N_);
  enc1_kernel<9><<<(N_ * 128 + 255) / 256, blk, 0, stream>>>(nfeat, F(11), F(12), h1n, N_);
  gemm64<GM_LN, false, false><<<tilesN, blk, 0, stream>>>(h1n, wne2T, nullptr, nullptr, F(14),
                                                          F(15), F(16), nullptr, xh, N_);
  edge_feat_kernel<<<(E_ + 255) / 256, blk, 0, stream>>>(edge_index, F(5), F(0), F(9), F(10),
                                                         efeat, E_);
  enc1_kernel<4><<<(E_ * 128 + 255) / 256, blk, 0, stream>>>(efeat, F(17), F(18), ehP, E_);
  gemm64<GM_LN, false, false><<<tilesE, blk, 0, stream>>>(ehP, wee2T, nullptr, nullptr, F(20),
                                                          F(21), F(22), nullptr, ehP, E_);

  // ---- process steps ----
  for (int i = 0; i < 3; ++i) {
    const u16* wtA = wpe1T + (size_t)(i * 3 + 0) * 16384;
    const u16* wtB = wpe1T + (size_t)(i * 3 + 1) * 16384;
    const u16* wtC = wpe1T + (size_t)(i * 3 + 2) * 16384;
    const float* pb1 = F(24) + i * 128;
    const u16* wt2 = wpe2T + (size_t)i * 16384;
    const float* pb2 = F(26) + i * 128;
    const float* pg = F(27) + i * 128;
    const float* pbe = F(28) + i * 128;
    const u16* wtnA = wpn1T + (size_t)(i * 2 + 0) * 16384;
    const u16* wtnB = wpn1T + (size_t)(i * 2 + 1) * 16384;
    const float* nb1 = F(30) + i * 128;
    const u16* wtn2 = wpn2T + (size_t)i * 16384;
    const float* nb2 = F(32) + i * 128;
    const float* ng = F(33) + i * 128;
    const float* nbe = F(34) + i * 128;

    gemm64_2w<<<tilesN, blk, 0, stream>>>(xh, wtA, wtB, xhA, xhB, N_);
    (void)hipMemsetAsync(aggr, 0, (size_t)N_ * 128 * 4, stream);
    edge_fused<<<tilesE, blk, 0, stream>>>(ehP, xhA, xhB, wtC, pb1, wt2, pb2, pg, pbe,
                                           edge_index, aggr, E_);
    gemm64<GM_RELU, true, true><<<tilesN, blk, 0, stream>>>(aggr, wtnA, xh, wtnB, nb1, nullptr,
                                                            nullptr, nullptr, h1n, N_);
    gemm64<GM_LN, false, false><<<tilesN, blk, 0, stream>>>(h1n, wtn2, nullptr, nullptr, nb2,
                                                            ng, nbe, xh, xh, N_);
  }

  // ---- decode ----
  decoder_kernel<<<(N_ + 3) / 4, blk, 0, stream>>>(xh, F(35), F(36), F(37), F(38),
                                                   (float*)d_out, N_);
}

// Round 10
// 1408.497 us; speedup vs baseline: 1.3553x; 1.0746x over previous
//
#include <hip/hip_runtime.h>
#include <stdint.h>

typedef unsigned short u16;
typedef __attribute__((ext_vector_type(8))) short bf16x8_t;
typedef __attribute__((ext_vector_type(4))) float f32x4_t;

__device__ __forceinline__ float bl(u16 x) {
  union { unsigned u; float f; } c; c.u = ((unsigned)x) << 16; return c.f;
}
__device__ __forceinline__ u16 fb(float x) {
  union { float f; unsigned u; } c; c.f = x;
  unsigned r = c.u + 0x7fffu + ((c.u >> 16) & 1u);
  return (u16)(r >> 16);
}

__global__ void sentinel_kernel(float* out, int n) {
  int i = blockIdx.x * 256 + threadIdx.x;
  if (i < n) out[i] = 12345.f;
}

// ---------------- weight transpose: wT[n][k] = fb(W[k][n]) ----------------
struct TSeg { const float* src; u16* dst; };
struct TArgs { TSeg s[23]; };
__global__ void transpose_w(TArgs a) {
  const float* src = a.s[blockIdx.x].src;
  u16* dst = a.s[blockIdx.x].dst;
  for (int e = threadIdx.x; e < 16384; e += 256) {
    int n = e >> 7, k = e & 127;
    dst[e] = fb(src[k * 128 + n]);
  }
}

// ---------------- CSR build ----------------
__global__ void zero_i32(int* p, int n) {
  int i = blockIdx.x * 256 + threadIdx.x;
  if (i < n) p[i] = 0;
}
__global__ void deg_count(const int* __restrict__ ei, int* __restrict__ cnt, int E) {
  int e = blockIdx.x * 256 + threadIdx.x;
  if (e < E) atomicAdd(&cnt[ei[E + e]], 1);
}
__global__ void scan1(const int* __restrict__ cnt, int* __restrict__ part,
                      int* __restrict__ bsum, int N) {
  __shared__ int s[256];
  int i = blockIdx.x * 256 + threadIdx.x;
  s[threadIdx.x] = (i < N) ? cnt[i] : 0;
  __syncthreads();
#pragma unroll
  for (int o = 1; o < 256; o <<= 1) {
    int t = (threadIdx.x >= o) ? s[threadIdx.x - o] : 0;
    __syncthreads();
    s[threadIdx.x] += t;
    __syncthreads();
  }
  if (i < N) part[i] = s[threadIdx.x];
  if (threadIdx.x == 255) bsum[blockIdx.x] = s[255];
}
__global__ void scan2(int* bsum, int nb) {
  if (threadIdx.x == 0 && blockIdx.x == 0) {
    int acc = 0;
    for (int i = 0; i < nb; ++i) { int t = bsum[i]; bsum[i] = acc; acc += t; }
  }
}
__global__ void scan3(const int* __restrict__ part, const int* __restrict__ bsum,
                      int* __restrict__ start, int N) {
  int i = blockIdx.x * 256 + threadIdx.x;
  if (i < N) start[i + 1] = part[i] + bsum[i >> 8];
  if (i == 0) start[0] = 0;
}
__global__ void fill_slot(const int* __restrict__ ei, int* __restrict__ cnt2,
                          const int* __restrict__ start, int* __restrict__ slotOf, int E) {
  int e = blockIdx.x * 256 + threadIdx.x;
  if (e >= E) return;
  int r = ei[E + e];
  int p = atomicAdd(&cnt2[r], 1);
  slotOf[e] = start[r] + p;
}

// ---------------- aggregate: aggrb[n] = sum msgbuf rows [start[n],start[n+1]) ----------------
__global__ void aggregate(const u16* __restrict__ msgbuf, const int* __restrict__ start,
                          u16* __restrict__ aggrb, int N) {
  int n = blockIdx.x * 16 + (threadIdx.x >> 4);
  int t = threadIdx.x & 15;
  if (n >= N) return;
  int b = start[n], e = start[n + 1];
  float acc[8] = {0, 0, 0, 0, 0, 0, 0, 0};
  for (int i = b; i < e; ++i) {
    u16 m8[8];
    *(uint4*)m8 = *(const uint4*)(msgbuf + (size_t)i * 128 + t * 8);
#pragma unroll
    for (int j = 0; j < 8; ++j) acc[j] += bl(m8[j]);
  }
  u16 o8[8];
#pragma unroll
  for (int j = 0; j < 8; ++j) o8[j] = fb(acc[j]);
  *(uint4*)(aggrb + (size_t)n * 128 + t * 8) = *(uint4*)o8;
}

// ---------------- feature kernels ----------------
__global__ void node_feat_kernel(const float* __restrict__ t, const float* __restrict__ tp,
                                 const float* __restrict__ q, const float* __restrict__ qp,
                                 const float* __restrict__ qn, const float* __restrict__ nm,
                                 const float* __restrict__ ns, float* __restrict__ nfeat,
                                 int n_nodes) {
  int n = blockIdx.x * 256 + threadIdx.x;
  if (n >= n_nodes) return;
  float u = t[n];
  float x[9];
  x[0] = u; x[1] = u - tp[n];
  float hq = q[n];
  x[2] = hq; x[3] = hq - qp[n];
#pragma unroll
  for (int j = 0; j < 5; ++j) x[4 + j] = qn[n * 5 + j];
#pragma unroll
  for (int k = 0; k < 9; ++k) nfeat[n * 9 + k] = (x[k] - nm[k]) / ns[k];
}

__global__ void edge_feat_kernel(const int* __restrict__ ei, const float* __restrict__ mp,
                                 const float* __restrict__ u, const float* __restrict__ em,
                                 const float* __restrict__ es, float* __restrict__ efeat,
                                 int n_edges) {
  int e = blockIdx.x * 256 + threadIdx.x;
  if (e >= n_edges) return;
  int s = ei[e], r = ei[n_edges + e];
  float rx = mp[s * 2] - mp[r * 2];
  float ry = mp[s * 2 + 1] - mp[r * 2 + 1];
  float d = sqrtf(rx * rx + ry * ry);
  float rt = u[s] - u[r];
  float x[4] = {rx, ry, d, rt};
#pragma unroll
  for (int k = 0; k < 4; ++k) efeat[e * 4 + k] = (x[k] - em[k]) / es[k];
}

template <int K>
__global__ void enc1_kernel(const float* __restrict__ feat, const float* __restrict__ w1,
                            const float* __restrict__ b1, u16* __restrict__ out, int M) {
  int gid = blockIdx.x * 256 + threadIdx.x;
  int n = gid >> 7, h = gid & 127;
  if (n >= M) return;
  float acc = b1[h];
#pragma unroll
  for (int k = 0; k < K; ++k) acc += feat[n * K + k] * w1[k * 128 + h];
  out[n * 128 + h] = fb(acc > 0.f ? acc : 0.f);
}

// ---------------- LDS-free-GEMM + LDS-staged vector-store epilogue ----------------
#define GM_NONE 0
#define GM_RELU 1
#define GM_LN 2

template <int MODE, bool DUAL, bool A0F32>
__global__ __launch_bounds__(256, 2) void gemm64(
    const void* __restrict__ A0v, const u16* __restrict__ WT0, const u16* __restrict__ A1,
    const u16* __restrict__ WT1, const float* __restrict__ bias, const float* __restrict__ gg,
    const float* __restrict__ bb, const u16* __restrict__ resid, u16* __restrict__ out, int M) {
  __shared__ u16 sO[64][136];
  const int tid = threadIdx.x;
  const int wave = tid >> 6, lane = tid & 63;
  const int q = lane >> 4, l16 = lane & 15;
  const int m0 = blockIdx.x * 64;
  int arow = m0 + wave * 16 + l16;
  if (arow >= M) arow = M - 1;

  f32x4_t acc[8];
#pragma unroll
  for (int b = 0; b < 8; ++b) acc[b] = (f32x4_t){0.f, 0.f, 0.f, 0.f};

  const int NKT = DUAL ? 2 : 1;
#pragma unroll 1
  for (int kt = 0; kt < NKT; ++kt) {
    const u16* WT = kt ? WT1 : WT0;
#pragma unroll
    for (int kk = 0; kk < 4; ++kk) {
      bf16x8_t af;
      if (A0F32 && kt == 0) {
        const float* ap = (const float*)A0v + (size_t)arow * 128 + kk * 32 + q * 8;
        union { u16 u[8]; bf16x8_t v; } cv;
#pragma unroll
        for (int j = 0; j < 8; ++j) cv.u[j] = fb(ap[j]);
        af = cv.v;
      } else {
        const u16* ap = (kt ? A1 : (const u16*)A0v) + (size_t)arow * 128 + kk * 32 + q * 8;
        af = *(const bf16x8_t*)ap;
      }
      const u16* wp = WT + kk * 32 + q * 8;
#pragma unroll
      for (int nt = 0; nt < 8; ++nt) {
        bf16x8_t bfv = *(const bf16x8_t*)(wp + (size_t)(nt * 16 + l16) * 128);
        acc[nt] = __builtin_amdgcn_mfma_f32_16x16x32_bf16(af, bfv, acc[nt], 0, 0, 0);
      }
    }
  }

  const int rowb = wave * 16 + q * 4;
  if (MODE == GM_NONE) {
#pragma unroll
    for (int r = 0; r < 4; ++r)
#pragma unroll
      for (int nt = 0; nt < 8; ++nt) sO[rowb + r][nt * 16 + l16] = fb(acc[nt][r]);
  } else if (MODE == GM_RELU) {
    float bcol[8];
#pragma unroll
    for (int nt = 0; nt < 8; ++nt) bcol[nt] = bias[nt * 16 + l16];
#pragma unroll
    for (int r = 0; r < 4; ++r)
#pragma unroll
      for (int nt = 0; nt < 8; ++nt) {
        float v = acc[nt][r] + bcol[nt];
        sO[rowb + r][nt * 16 + l16] = fb(v > 0.f ? v : 0.f);
      }
  } else {
    float bcol[8], gcol[8], becol[8];
#pragma unroll
    for (int nt = 0; nt < 8; ++nt) {
      bcol[nt] = bias[nt * 16 + l16];
      gcol[nt] = gg[nt * 16 + l16];
      becol[nt] = bb[nt * 16 + l16];
    }
    float s[4] = {0, 0, 0, 0}, ss[4] = {0, 0, 0, 0};
#pragma unroll
    for (int r = 0; r < 4; ++r)
#pragma unroll
      for (int nt = 0; nt < 8; ++nt) {
        float v = acc[nt][r] + bcol[nt];
        s[r] += v;
        ss[r] += v * v;
      }
#pragma unroll
    for (int r = 0; r < 4; ++r) {
#pragma unroll
      for (int m = 1; m <= 8; m <<= 1) {
        s[r] += __shfl_xor(s[r], m, 64);
        ss[r] += __shfl_xor(ss[r], m, 64);
      }
    }
#pragma unroll
    for (int r = 0; r < 4; ++r) {
      float mean = s[r] * (1.f / 128.f);
      float var = fmaxf(ss[r] * (1.f / 128.f) - mean * mean, 0.f);
      float rstd = rsqrtf(var + 1e-5f);
#pragma unroll
      for (int nt = 0; nt < 8; ++nt) {
        float v = (acc[nt][r] + bcol[nt] - mean) * rstd * gcol[nt] + becol[nt];
        sO[rowb + r][nt * 16 + l16] = fb(v);
      }
    }
  }
  __syncthreads();
#pragma unroll
  for (int it = 0; it < 4; ++it) {
    int lin = it * 256 + tid;
    int row = lin >> 4, ch = (lin & 15) * 8;
    int grow = m0 + row;
    if (grow >= M) continue;
    u16 o8[8];
    *(uint4*)o8 = *(uint4*)(&sO[row][ch]);
    if (MODE == GM_LN && resid) {
      u16 r8[8];
      *(uint4*)r8 = *(const uint4*)(resid + (size_t)grow * 128 + ch);
#pragma unroll
      for (int j = 0; j < 8; ++j) o8[j] = fb(bl(o8[j]) + bl(r8[j]));
    }
    *(uint4*)(out + (size_t)grow * 128 + ch) = *(uint4*)o8;
  }
}

// dual-output GEMM: out0 = A@W0, out1 = A@W1 (A read once)
__global__ __launch_bounds__(256, 2) void gemm64_2w(
    const u16* __restrict__ A, const u16* __restrict__ WT0, const u16* __restrict__ WT1,
    u16* __restrict__ out0, u16* __restrict__ out1, int M) {
  __shared__ u16 sO0[64][136];
  __shared__ u16 sO1[64][136];
  const int tid = threadIdx.x;
  const int wave = tid >> 6, lane = tid & 63;
  const int q = lane >> 4, l16 = lane & 15;
  const int m0 = blockIdx.x * 64;
  int arow = m0 + wave * 16 + l16;
  if (arow >= M) arow = M - 1;

  f32x4_t a0[8], a1[8];
#pragma unroll
  for (int b = 0; b < 8; ++b) {
    a0[b] = (f32x4_t){0.f, 0.f, 0.f, 0.f};
    a1[b] = (f32x4_t){0.f, 0.f, 0.f, 0.f};
  }
#pragma unroll 2
  for (int kk = 0; kk < 4; ++kk) {
    bf16x8_t af = *(const bf16x8_t*)(A + (size_t)arow * 128 + kk * 32 + q * 8);
#pragma unroll
    for (int nt = 0; nt < 8; ++nt) {
      bf16x8_t b0 = *(const bf16x8_t*)(WT0 + (size_t)(nt * 16 + l16) * 128 + kk * 32 + q * 8);
      bf16x8_t b1v = *(const bf16x8_t*)(WT1 + (size_t)(nt * 16 + l16) * 128 + kk * 32 + q * 8);
      a0[nt] = __builtin_amdgcn_mfma_f32_16x16x32_bf16(af, b0, a0[nt], 0, 0, 0);
      a1[nt] = __builtin_amdgcn_mfma_f32_16x16x32_bf16(af, b1v, a1[nt], 0, 0, 0);
    }
  }
  const int rowb = wave * 16 + q * 4;
#pragma unroll
  for (int r = 0; r < 4; ++r)
#pragma unroll
    for (int nt = 0; nt < 8; ++nt) {
      sO0[rowb + r][nt * 16 + l16] = fb(a0[nt][r]);
      sO1[rowb + r][nt * 16 + l16] = fb(a1[nt][r]);
    }
  __syncthreads();
#pragma unroll
  for (int it = 0; it < 4; ++it) {
    int lin = it * 256 + tid;
    int row = lin >> 4, ch = (lin & 15) * 8;
    int grow = m0 + row;
    if (grow >= M) continue;
    *(uint4*)(out0 + (size_t)grow * 128 + ch) = *(uint4*)(&sO0[row][ch]);
    *(uint4*)(out1 + (size_t)grow * 128 + ch) = *(uint4*)(&sO1[row][ch]);
  }
}

// ---------------- fused edge kernel ----------------
// CSR=true: msg rows -> msgbuf[slotOf[e]]; CSR=false: atomic scatter into scat.
template <bool CSR>
__global__ __launch_bounds__(256, 2) void edge_fused(
    u16* __restrict__ eh, const u16* __restrict__ xhA, const u16* __restrict__ xhB,
    const u16* __restrict__ wtC, const float* __restrict__ b1, const u16* __restrict__ wt2,
    const float* __restrict__ b2, const float* __restrict__ gg, const float* __restrict__ bb,
    const int* __restrict__ ei, const int* __restrict__ slotOf, u16* __restrict__ msgbuf,
    float* __restrict__ scat, int E) {
  __shared__ u16 sHm[64][136];
  __shared__ u16 sHe[64][136];
  __shared__ int sS[64], sR[64], sSlot[64];
  const int tid = threadIdx.x;
  const int wave = tid >> 6, lane = tid & 63;
  const int q = lane >> 4, l16 = lane & 15;
  const int m0 = blockIdx.x * 64;
  const int rowb = wave * 16 + q * 4;
  int arow = m0 + wave * 16 + l16;
  int arc = arow < E ? arow : E - 1;

  if (tid < 64) {
    int e = m0 + tid;
    sS[tid] = (e < E) ? ei[e] : 0;
    sR[tid] = (e < E) ? ei[E + e] : 0;
    if (CSR) sSlot[tid] = (e < E) ? slotOf[e] : 0;
  }

  // phase 1: T = eh @ WC
  f32x4_t accC[8];
#pragma unroll
  for (int b = 0; b < 8; ++b) accC[b] = (f32x4_t){0.f, 0.f, 0.f, 0.f};
#pragma unroll
  for (int kk = 0; kk < 4; ++kk) {
    bf16x8_t af = *(const bf16x8_t*)(eh + (size_t)arc * 128 + kk * 32 + q * 8);
#pragma unroll
    for (int nt = 0; nt < 8; ++nt) {
      bf16x8_t bfv = *(const bf16x8_t*)(wtC + (size_t)(nt * 16 + l16) * 128 + kk * 32 + q * 8);
      accC[nt] = __builtin_amdgcn_mfma_f32_16x16x32_bf16(af, bfv, accC[nt], 0, 0, 0);
    }
  }
  // T -> sHm (C-layout)
#pragma unroll
  for (int r = 0; r < 4; ++r)
#pragma unroll
    for (int nt = 0; nt < 8; ++nt) sHm[rowb + r][nt * 16 + l16] = fb(accC[nt][r]);
  __syncthreads();

  // phase 2: row-wise vectorized gather + ReLU; sHm <- H_msg, sHe <- H_edge
#pragma unroll
  for (int it = 0; it < 4; ++it) {
    int lin = it * 256 + tid;
    int row = lin >> 4, ch = (lin & 15) * 8;
    bool ok = (m0 + row) < E;
    int s_ = sS[row], r_ = sR[row];
    u16 t8[8], ar[8], as_[8], br[8], bs[8], hm[8], he[8];
    *(uint4*)t8 = *(uint4*)(&sHm[row][ch]);
    *(uint4*)ar = *(const uint4*)(xhA + (size_t)r_ * 128 + ch);
    *(uint4*)as_ = *(const uint4*)(xhA + (size_t)s_ * 128 + ch);
    *(uint4*)br = *(const uint4*)(xhB + (size_t)r_ * 128 + ch);
    *(uint4*)bs = *(const uint4*)(xhB + (size_t)s_ * 128 + ch);
#pragma unroll
    for (int j = 0; j < 8; ++j) {
      float t = bl(t8[j]) + b1[ch + j];
      float vm = t + bl(ar[j]) + bl(bs[j]);
      float ve = t + bl(as_[j]) + bl(br[j]);
      hm[j] = (ok && vm > 0.f) ? fb(vm) : 0;
      he[j] = (ok && ve > 0.f) ? fb(ve) : 0;
    }
    *(uint4*)(&sHm[row][ch]) = *(uint4*)hm;
    *(uint4*)(&sHe[row][ch]) = *(uint4*)he;
  }
  __syncthreads();

  float bcol[8], gcol[8], becol[8];
#pragma unroll
  for (int nt = 0; nt < 8; ++nt) {
    bcol[nt] = b2[nt * 16 + l16];
    gcol[nt] = gg[nt * 16 + l16];
    becol[nt] = bb[nt * 16 + l16];
  }

  // phase 3: both GEMMs back-to-back (reads of sHm/sHe), then LN stats
  f32x4_t accM[8], accE[8];
#pragma unroll
  for (int b = 0; b < 8; ++b) {
    accM[b] = (f32x4_t){0.f, 0.f, 0.f, 0.f};
    accE[b] = (f32x4_t){0.f, 0.f, 0.f, 0.f};
  }
#pragma unroll
  for (int kk = 0; kk < 4; ++kk) {
    bf16x8_t afm = *(const bf16x8_t*)(&sHm[wave * 16 + l16][kk * 32 + q * 8]);
    bf16x8_t afe = *(const bf16x8_t*)(&sHe[wave * 16 + l16][kk * 32 + q * 8]);
#pragma unroll
    for (int nt = 0; nt < 8; ++nt) {
      bf16x8_t bfv = *(const bf16x8_t*)(wt2 + (size_t)(nt * 16 + l16) * 128 + kk * 32 + q * 8);
      accM[nt] = __builtin_amdgcn_mfma_f32_16x16x32_bf16(afm, bfv, accM[nt], 0, 0, 0);
      accE[nt] = __builtin_amdgcn_mfma_f32_16x16x32_bf16(afe, bfv, accE[nt], 0, 0, 0);
    }
  }
  float sm[4] = {0, 0, 0, 0}, ssm[4] = {0, 0, 0, 0};
  float se[4] = {0, 0, 0, 0}, sse[4] = {0, 0, 0, 0};
#pragma unroll
  for (int r = 0; r < 4; ++r)
#pragma unroll
    for (int nt = 0; nt < 8; ++nt) {
      float vm = accM[nt][r] + bcol[nt];
      float ve = accE[nt][r] + bcol[nt];
      sm[r] += vm; ssm[r] += vm * vm;
      se[r] += ve; sse[r] += ve * ve;
    }
#pragma unroll
  for (int r = 0; r < 4; ++r) {
#pragma unroll
    for (int m = 1; m <= 8; m <<= 1) {
      sm[r] += __shfl_xor(sm[r], m, 64);
      ssm[r] += __shfl_xor(ssm[r], m, 64);
      se[r] += __shfl_xor(se[r], m, 64);
      sse[r] += __shfl_xor(sse[r], m, 64);
    }
  }

  if (!CSR) {
    // atomic fallback: scatter Ym directly
#pragma unroll
    for (int r = 0; r < 4; ++r) {
      int row = m0 + rowb + r;
      if (row >= E) continue;
      int rr = sR[rowb + r];
      float mean = sm[r] * (1.f / 128.f);
      float var = fmaxf(ssm[r] * (1.f / 128.f) - mean * mean, 0.f);
      float rstd = rsqrtf(var + 1e-5f);
#pragma unroll
      for (int nt = 0; nt < 8; ++nt) {
        float v = (accM[nt][r] + bcol[nt] - mean) * rstd * gcol[nt] + becol[nt];
        atomicAdd(&scat[(size_t)rr * 128 + nt * 16 + l16], v);
      }
    }
  }

  __syncthreads();  // all LDS reads done; safe to overwrite
  // stage Ym (CSR) and Ye into LDS
#pragma unroll
  for (int r = 0; r < 4; ++r) {
    float meanE = se[r] * (1.f / 128.f);
    float varE = fmaxf(sse[r] * (1.f / 128.f) - meanE * meanE, 0.f);
    float rstdE = rsqrtf(varE + 1e-5f);
    float meanM = sm[r] * (1.f / 128.f);
    float varM = fmaxf(ssm[r] * (1.f / 128.f) - meanM * meanM, 0.f);
    float rstdM = rsqrtf(varM + 1e-5f);
#pragma unroll
    for (int nt = 0; nt < 8; ++nt) {
      float ve = (accE[nt][r] + bcol[nt] - meanE) * rstdE * gcol[nt] + becol[nt];
      sHe[rowb + r][nt * 16 + l16] = fb(ve);
      if (CSR) {
        float vm = (accM[nt][r] + bcol[nt] - meanM) * rstdM * gcol[nt] + becol[nt];
        sHm[rowb + r][nt * 16 + l16] = fb(vm);
      }
    }
  }
  __syncthreads();
  // row-wise vector stores: msg -> msgbuf[slot], Ye+eh -> eh
#pragma unroll
  for (int it = 0; it < 4; ++it) {
    int lin = it * 256 + tid;
    int row = lin >> 4, ch = (lin & 15) * 8;
    int grow = m0 + row;
    if (grow >= E) continue;
    if (CSR) {
      int slot = sSlot[row];
      *(uint4*)(msgbuf + (size_t)slot * 128 + ch) = *(uint4*)(&sHm[row][ch]);
    }
    u16 y8[8], e8[8];
    *(uint4*)y8 = *(uint4*)(&sHe[row][ch]);
    *(uint4*)e8 = *(const uint4*)(eh + (size_t)grow * 128 + ch);
#pragma unroll
    for (int j = 0; j < 8; ++j) y8[j] = fb(bl(y8[j]) + bl(e8[j]));
    *(uint4*)(eh + (size_t)grow * 128 + ch) = *(uint4*)y8;
  }
}

// decoder: wave per node, 128->64 swish -> 64->5, times dt
__global__ void decoder_kernel(const u16* __restrict__ xh, const float* __restrict__ w1,
                               const float* __restrict__ b1, const float* __restrict__ w2,
                               const float* __restrict__ b2, float* __restrict__ out,
                               int n_nodes) {
  __shared__ float sx[4][128];
  int tid = threadIdx.x;
  int lw = tid >> 6, lane = tid & 63;
  int n0 = blockIdx.x * 4;
  for (int i = tid; i < 512; i += 256) {
    int nn = i >> 7, c = i & 127;
    int n = n0 + nn;
    sx[nn][c] = (n < n_nodes) ? bl(xh[(size_t)n * 128 + c]) : 0.f;
  }
  __syncthreads();
  int n = n0 + lw;
  float h = b1[lane];
#pragma unroll 16
  for (int k = 0; k < 128; ++k) h += sx[lw][k] * w1[k * 64 + lane];
  float hs = h * (1.f / (1.f + __expf(-h)));
  float d[5];
#pragma unroll
  for (int t = 0; t < 5; ++t) {
    float p = hs * w2[lane * 5 + t];
#pragma unroll
    for (int m = 1; m <= 32; m <<= 1) p += __shfl_xor(p, m, 64);
    d[t] = p;
  }
  if (lane == 0 && n < n_nodes) {
#pragma unroll
    for (int t = 0; t < 5; ++t)
      out[(size_t)n * 5 + t] = (float)(t + 1) * (d[t] + b2[t]);
  }
}

extern "C" void kernel_launch(void* const* d_in, const int* in_sizes, int n_in, void* d_out,
                              int out_size, void* d_ws, size_t ws_size, hipStream_t stream) {
  auto F = [&](int i) { return (const float*)d_in[i]; };
  const int* edge_index = (const int*)d_in[6];
  const int N_ = in_sizes[0];
  const int E_ = in_sizes[6] / 2;

  char* wsb = (char*)d_ws;
  size_t off = 0;
  auto alloc = [&](size_t bytes) -> char* {
    char* p = wsb + off;
    off += (bytes + 255) & ~(size_t)255;
    return p;
  };
  u16* xh = (u16*)alloc((size_t)N_ * 128 * 2);
  u16* xhA = (u16*)alloc((size_t)N_ * 128 * 2);
  u16* xhB = (u16*)alloc((size_t)N_ * 128 * 2);
  u16* h1n = (u16*)alloc((size_t)N_ * 128 * 2);
  u16* ehP = (u16*)alloc((size_t)E_ * 128 * 2);
  float* nfeat = (float*)xhA;  // alias (dead before xhA live)
  float* efeat = (float*)xhB;  // alias
  u16* aggrb = xhA;            // alias (xhA dead after edge_fused)
  u16* wne2T = (u16*)alloc(16384 * 2);
  u16* wee2T = (u16*)alloc(16384 * 2);
  u16* wpe1T = (u16*)alloc((size_t)9 * 16384 * 2);
  u16* wpe2T = (u16*)alloc((size_t)3 * 16384 * 2);
  u16* wpn1T = (u16*)alloc((size_t)6 * 16384 * 2);
  u16* wpn2T = (u16*)alloc((size_t)3 * 16384 * 2);

  const size_t base_off = off;
  // CSR-path extras
  int* startp = (int*)alloc((size_t)(N_ + 1) * 4);
  int* cntp = (int*)alloc((size_t)N_ * 4);
  int* partp = (int*)alloc((size_t)N_ * 4);
  int* bsump = (int*)alloc(((size_t)(N_ + 255) / 256) * 4 + 256);
  int* slotOf = (int*)alloc((size_t)E_ * 4);
  u16* msgbuf = (u16*)alloc((size_t)E_ * 128 * 2);
  bool useCSR = (off <= ws_size);
  float* aggrf = nullptr;
  if (!useCSR) {
    off = base_off;
    aggrf = (float*)alloc((size_t)N_ * 128 * 4);
    if (off > ws_size) {
      sentinel_kernel<<<(out_size + 255) / 256, 256, 0, stream>>>((float*)d_out, out_size);
      return;
    }
  }

  TArgs ta;
  int ts = 0;
  ta.s[ts++] = {F(13), wne2T};
  ta.s[ts++] = {F(19), wee2T};
  for (int i = 0; i < 3; ++i)
    for (int b = 0; b < 3; ++b)
      ta.s[ts++] = {F(23) + (size_t)(i * 3 + b) * 16384, wpe1T + (size_t)(i * 3 + b) * 16384};
  for (int i = 0; i < 3; ++i) ta.s[ts++] = {F(25) + (size_t)i * 16384, wpe2T + (size_t)i * 16384};
  for (int i = 0; i < 3; ++i)
    for (int b = 0; b < 2; ++b)
      ta.s[ts++] = {F(29) + (size_t)(i * 2 + b) * 16384, wpn1T + (size_t)(i * 2 + b) * 16384};
  for (int i = 0; i < 3; ++i) ta.s[ts++] = {F(31) + (size_t)i * 16384, wpn2T + (size_t)i * 16384};

  const int tilesN = (N_ + 63) / 64;
  const int tilesE = (E_ + 63) / 64;
  const int nb = (N_ + 255) / 256;
  dim3 blk(256);

  transpose_w<<<23, blk, 0, stream>>>(ta);

  if (useCSR) {
    zero_i32<<<(N_ + 255) / 256, blk, 0, stream>>>(cntp, N_);
    deg_count<<<(E_ + 255) / 256, blk, 0, stream>>>(edge_index, cntp, E_);
    scan1<<<nb, blk, 0, stream>>>(cntp, partp, bsump, N_);
    scan2<<<1, blk, 0, stream>>>(bsump, nb);
    scan3<<<nb, blk, 0, stream>>>(partp, bsump, startp, N_);
    zero_i32<<<(N_ + 255) / 256, blk, 0, stream>>>(cntp, N_);
    fill_slot<<<(E_ + 255) / 256, blk, 0, stream>>>(edge_index, cntp, startp, slotOf, E_);
  }

  // ---- encode ----
  node_feat_kernel<<<(N_ + 255) / 256, blk, 0, stream>>>(F(0), F(1), F(2), F(3), F(4), F(7),
                                                         F(8), nfeat, N_);
  enc1_kernel<9><<<(N_ * 128 + 255) / 256, blk, 0, stream>>>(nfeat, F(11), F(12), h1n, N_);
  gemm64<GM_LN, false, false><<<tilesN, blk, 0, stream>>>(h1n, wne2T, nullptr, nullptr, F(14),
                                                          F(15), F(16), nullptr, xh, N_);
  edge_feat_kernel<<<(E_ + 255) / 256, blk, 0, stream>>>(edge_index, F(5), F(0), F(9), F(10),
                                                         efeat, E_);
  enc1_kernel<4><<<(E_ * 128 + 255) / 256, blk, 0, stream>>>(efeat, F(17), F(18), ehP, E_);
  gemm64<GM_LN, false, false><<<tilesE, blk, 0, stream>>>(ehP, wee2T, nullptr, nullptr, F(20),
                                                          F(21), F(22), nullptr, ehP, E_);

  // ---- process steps ----
  for (int i = 0; i < 3; ++i) {
    const u16* wtA = wpe1T + (size_t)(i * 3 + 0) * 16384;
    const u16* wtB = wpe1T + (size_t)(i * 3 + 1) * 16384;
    const u16* wtC = wpe1T + (size_t)(i * 3 + 2) * 16384;
    const float* pb1 = F(24) + i * 128;
    const u16* wt2 = wpe2T + (size_t)i * 16384;
    const float* pb2 = F(26) + i * 128;
    const float* pg = F(27) + i * 128;
    const float* pbe = F(28) + i * 128;
    const u16* wtnA = wpn1T + (size_t)(i * 2 + 0) * 16384;
    const u16* wtnB = wpn1T + (size_t)(i * 2 + 1) * 16384;
    const float* nb1 = F(30) + i * 128;
    const u16* wtn2 = wpn2T + (size_t)i * 16384;
    const float* nb2 = F(32) + i * 128;
    const float* ng = F(33) + i * 128;
    const float* nbe = F(34) + i * 128;

    gemm64_2w<<<tilesN, blk, 0, stream>>>(xh, wtA, wtB, xhA, xhB, N_);
    if (useCSR) {
      edge_fused<true><<<tilesE, blk, 0, stream>>>(ehP, xhA, xhB, wtC, pb1, wt2, pb2, pg, pbe,
                                                   edge_index, slotOf, msgbuf, nullptr, E_);
      aggregate<<<(N_ + 15) / 16, blk, 0, stream>>>(msgbuf, startp, aggrb, N_);
      gemm64<GM_RELU, true, false><<<tilesN, blk, 0, stream>>>(aggrb, wtnA, xh, wtnB, nb1,
                                                               nullptr, nullptr, nullptr, h1n,
                                                               N_);
    } else {
      (void)hipMemsetAsync(aggrf, 0, (size_t)N_ * 128 * 4, stream);
      edge_fused<false><<<tilesE, blk, 0, stream>>>(ehP, xhA, xhB, wtC, pb1, wt2, pb2, pg, pbe,
                                                    edge_index, nullptr, nullptr, aggrf, E_);
      gemm64<GM_RELU, true, true><<<tilesN, blk, 0, stream>>>(aggrf, wtnA, xh, wtnB, nb1,
                                                              nullptr, nullptr, nullptr, h1n,
                                                              N_);
    }
    gemm64<GM_LN, false, false><<<tilesN, blk, 0, stream>>>(h1n, wtn2, nullptr, nullptr, nb2,
                                                            ng, nbe, xh, xh, N_);
  }

  // ---- decode ----
  decoder_kernel<<<(N_ + 3) / 4, blk, 0, stream>>>(xh, F(35), F(36), F(37), F(38),
                                                   (float*)d_out, N_);
}

// Round 11
// 1375.605 us; speedup vs baseline: 1.3877x; 1.0239x over previous
//
#include <hip/hip_runtime.h>
#include <stdint.h>

typedef unsigned short u16;
typedef __attribute__((ext_vector_type(8))) short bf16x8_t;
typedef __attribute__((ext_vector_type(4))) float f32x4_t;

__device__ __forceinline__ float bl(u16 x) {
  union { unsigned u; float f; } c; c.u = ((unsigned)x) << 16; return c.f;
}
__device__ __forceinline__ u16 fb(float x) {
  union { float f; unsigned u; } c; c.f = x;
  unsigned r = c.u + 0x7fffu + ((c.u >> 16) & 1u);
  return (u16)(r >> 16);
}

__global__ void sentinel_kernel(float* out, int n) {
  int i = blockIdx.x * 256 + threadIdx.x;
  if (i < n) out[i] = 12345.f;
}

// ---------------- weight transpose: wT[n][k] = fb(W[k][n]) ----------------
struct TSeg { const float* src; u16* dst; };
struct TArgs { TSeg s[23]; };
__global__ void transpose_w(TArgs a) {
  const float* src = a.s[blockIdx.x].src;
  u16* dst = a.s[blockIdx.x].dst;
  for (int e = threadIdx.x; e < 16384; e += 256) {
    int n = e >> 7, k = e & 127;
    dst[e] = fb(src[k * 128 + n]);
  }
}

// ---------------- CSR build + receiver-sort ----------------
__global__ void zero_i32(int* p, int n) {
  int i = blockIdx.x * 256 + threadIdx.x;
  if (i < n) p[i] = 0;
}
__global__ void deg_count(const int* __restrict__ ei, int* __restrict__ cnt, int E) {
  int e = blockIdx.x * 256 + threadIdx.x;
  if (e < E) atomicAdd(&cnt[ei[E + e]], 1);
}
__global__ void scan1(const int* __restrict__ cnt, int* __restrict__ part,
                      int* __restrict__ bsum, int N) {
  __shared__ int s[256];
  int i = blockIdx.x * 256 + threadIdx.x;
  s[threadIdx.x] = (i < N) ? cnt[i] : 0;
  __syncthreads();
#pragma unroll
  for (int o = 1; o < 256; o <<= 1) {
    int t = (threadIdx.x >= o) ? s[threadIdx.x - o] : 0;
    __syncthreads();
    s[threadIdx.x] += t;
    __syncthreads();
  }
  if (i < N) part[i] = s[threadIdx.x];
  if (threadIdx.x == 255) bsum[blockIdx.x] = s[255];
}
__global__ void scan2(int* bsum, int nb) {
  if (threadIdx.x == 0 && blockIdx.x == 0) {
    int acc = 0;
    for (int i = 0; i < nb; ++i) { int t = bsum[i]; bsum[i] = acc; acc += t; }
  }
}
__global__ void scan3(const int* __restrict__ part, const int* __restrict__ bsum,
                      int* __restrict__ start, int N) {
  int i = blockIdx.x * 256 + threadIdx.x;
  if (i < N) start[i + 1] = part[i] + bsum[i >> 8];
  if (i == 0) start[0] = 0;
}
// assign slot per edge; emit receiver-sorted sender/receiver arrays
__global__ void fill_slot(const int* __restrict__ ei, int* __restrict__ cnt2,
                          const int* __restrict__ start, int* __restrict__ sortedS,
                          int* __restrict__ sortedR, int E) {
  int e = blockIdx.x * 256 + threadIdx.x;
  if (e >= E) return;
  int s = ei[e], r = ei[E + e];
  int p = atomicAdd(&cnt2[r], 1);
  int slot = start[r] + p;
  sortedS[slot] = s;
  sortedR[slot] = r;
}

// ---------------- aggregate: aggrb[n] = sum msgbuf rows [start[n],start[n+1]) ----------------
__global__ void aggregate(const u16* __restrict__ msgbuf, const int* __restrict__ start,
                          u16* __restrict__ aggrb, int N) {
  int n = blockIdx.x * 16 + (threadIdx.x >> 4);
  int t = threadIdx.x & 15;
  if (n >= N) return;
  int b = start[n], e = start[n + 1];
  float acc[8] = {0, 0, 0, 0, 0, 0, 0, 0};
  for (int i = b; i < e; ++i) {
    u16 m8[8];
    *(uint4*)m8 = *(const uint4*)(msgbuf + (size_t)i * 128 + t * 8);
#pragma unroll
    for (int j = 0; j < 8; ++j) acc[j] += bl(m8[j]);
  }
  u16 o8[8];
#pragma unroll
  for (int j = 0; j < 8; ++j) o8[j] = fb(acc[j]);
  *(uint4*)(aggrb + (size_t)n * 128 + t * 8) = *(uint4*)o8;
}

// ---------------- feature kernels ----------------
__global__ void node_feat_kernel(const float* __restrict__ t, const float* __restrict__ tp,
                                 const float* __restrict__ q, const float* __restrict__ qp,
                                 const float* __restrict__ qn, const float* __restrict__ nm,
                                 const float* __restrict__ ns, float* __restrict__ nfeat,
                                 int n_nodes) {
  int n = blockIdx.x * 256 + threadIdx.x;
  if (n >= n_nodes) return;
  float u = t[n];
  float x[9];
  x[0] = u; x[1] = u - tp[n];
  float hq = q[n];
  x[2] = hq; x[3] = hq - qp[n];
#pragma unroll
  for (int j = 0; j < 5; ++j) x[4 + j] = qn[n * 5 + j];
#pragma unroll
  for (int k = 0; k < 9; ++k) nfeat[n * 9 + k] = (x[k] - nm[k]) / ns[k];
}

// edge features; sArr/rArr indexed by output row (sorted order in CSR mode)
__global__ void edge_feat_kernel(const int* __restrict__ sArr, const int* __restrict__ rArr,
                                 const float* __restrict__ mp, const float* __restrict__ u,
                                 const float* __restrict__ em, const float* __restrict__ es,
                                 float* __restrict__ efeat, int n_edges) {
  int e = blockIdx.x * 256 + threadIdx.x;
  if (e >= n_edges) return;
  int s = sArr[e], r = rArr[e];
  float rx = mp[s * 2] - mp[r * 2];
  float ry = mp[s * 2 + 1] - mp[r * 2 + 1];
  float d = sqrtf(rx * rx + ry * ry);
  float rt = u[s] - u[r];
  float x[4] = {rx, ry, d, rt};
#pragma unroll
  for (int k = 0; k < 4; ++k) efeat[e * 4 + k] = (x[k] - em[k]) / es[k];
}

template <int K>
__global__ void enc1_kernel(const float* __restrict__ feat, const float* __restrict__ w1,
                            const float* __restrict__ b1, u16* __restrict__ out, int M) {
  int gid = blockIdx.x * 256 + threadIdx.x;
  int n = gid >> 7, h = gid & 127;
  if (n >= M) return;
  float acc = b1[h];
#pragma unroll
  for (int k = 0; k < K; ++k) acc += feat[n * K + k] * w1[k * 128 + h];
  out[n * 128 + h] = fb(acc > 0.f ? acc : 0.f);
}

// ---------------- LDS-free-GEMM + LDS-staged vector-store epilogue ----------------
#define GM_NONE 0
#define GM_RELU 1
#define GM_LN 2

template <int MODE, bool DUAL, bool A0F32>
__global__ __launch_bounds__(256, 2) void gemm64(
    const void* __restrict__ A0v, const u16* __restrict__ WT0, const u16* __restrict__ A1,
    const u16* __restrict__ WT1, const float* __restrict__ bias, const float* __restrict__ gg,
    const float* __restrict__ bb, const u16* __restrict__ resid, u16* __restrict__ out, int M) {
  __shared__ u16 sO[64][136];
  const int tid = threadIdx.x;
  const int wave = tid >> 6, lane = tid & 63;
  const int q = lane >> 4, l16 = lane & 15;
  const int m0 = blockIdx.x * 64;
  int arow = m0 + wave * 16 + l16;
  if (arow >= M) arow = M - 1;

  f32x4_t acc[8];
#pragma unroll
  for (int b = 0; b < 8; ++b) acc[b] = (f32x4_t){0.f, 0.f, 0.f, 0.f};

  const int NKT = DUAL ? 2 : 1;
#pragma unroll 1
  for (int kt = 0; kt < NKT; ++kt) {
    const u16* WT = kt ? WT1 : WT0;
#pragma unroll
    for (int kk = 0; kk < 4; ++kk) {
      bf16x8_t af;
      if (A0F32 && kt == 0) {
        const float* ap = (const float*)A0v + (size_t)arow * 128 + kk * 32 + q * 8;
        union { u16 u[8]; bf16x8_t v; } cv;
#pragma unroll
        for (int j = 0; j < 8; ++j) cv.u[j] = fb(ap[j]);
        af = cv.v;
      } else {
        const u16* ap = (kt ? A1 : (const u16*)A0v) + (size_t)arow * 128 + kk * 32 + q * 8;
        af = *(const bf16x8_t*)ap;
      }
      const u16* wp = WT + kk * 32 + q * 8;
#pragma unroll
      for (int nt = 0; nt < 8; ++nt) {
        bf16x8_t bfv = *(const bf16x8_t*)(wp + (size_t)(nt * 16 + l16) * 128);
        acc[nt] = __builtin_amdgcn_mfma_f32_16x16x32_bf16(af, bfv, acc[nt], 0, 0, 0);
      }
    }
  }

  const int rowb = wave * 16 + q * 4;
  if (MODE == GM_NONE) {
#pragma unroll
    for (int r = 0; r < 4; ++r)
#pragma unroll
      for (int nt = 0; nt < 8; ++nt) sO[rowb + r][nt * 16 + l16] = fb(acc[nt][r]);
  } else if (MODE == GM_RELU) {
    float bcol[8];
#pragma unroll
    for (int nt = 0; nt < 8; ++nt) bcol[nt] = bias[nt * 16 + l16];
#pragma unroll
    for (int r = 0; r < 4; ++r)
#pragma unroll
      for (int nt = 0; nt < 8; ++nt) {
        float v = acc[nt][r] + bcol[nt];
        sO[rowb + r][nt * 16 + l16] = fb(v > 0.f ? v : 0.f);
      }
  } else {
    float bcol[8], gcol[8], becol[8];
#pragma unroll
    for (int nt = 0; nt < 8; ++nt) {
      bcol[nt] = bias[nt * 16 + l16];
      gcol[nt] = gg[nt * 16 + l16];
      becol[nt] = bb[nt * 16 + l16];
    }
    float s[4] = {0, 0, 0, 0}, ss[4] = {0, 0, 0, 0};
#pragma unroll
    for (int r = 0; r < 4; ++r)
#pragma unroll
      for (int nt = 0; nt < 8; ++nt) {
        float v = acc[nt][r] + bcol[nt];
        s[r] += v;
        ss[r] += v * v;
      }
#pragma unroll
    for (int r = 0; r < 4; ++r) {
#pragma unroll
      for (int m = 1; m <= 8; m <<= 1) {
        s[r] += __shfl_xor(s[r], m, 64);
        ss[r] += __shfl_xor(ss[r], m, 64);
      }
    }
#pragma unroll
    for (int r = 0; r < 4; ++r) {
      float mean = s[r] * (1.f / 128.f);
      float var = fmaxf(ss[r] * (1.f / 128.f) - mean * mean, 0.f);
      float rstd = rsqrtf(var + 1e-5f);
#pragma unroll
      for (int nt = 0; nt < 8; ++nt) {
        float v = (acc[nt][r] + bcol[nt] - mean) * rstd * gcol[nt] + becol[nt];
        sO[rowb + r][nt * 16 + l16] = fb(v);
      }
    }
  }
  __syncthreads();
#pragma unroll
  for (int it = 0; it < 4; ++it) {
    int lin = it * 256 + tid;
    int row = lin >> 4, ch = (lin & 15) * 8;
    int grow = m0 + row;
    if (grow >= M) continue;
    u16 o8[8];
    *(uint4*)o8 = *(uint4*)(&sO[row][ch]);
    if (MODE == GM_LN && resid) {
      u16 r8[8];
      *(uint4*)r8 = *(const uint4*)(resid + (size_t)grow * 128 + ch);
#pragma unroll
      for (int j = 0; j < 8; ++j) o8[j] = fb(bl(o8[j]) + bl(r8[j]));
    }
    *(uint4*)(out + (size_t)grow * 128 + ch) = *(uint4*)o8;
  }
}

// dual-output GEMM: out0 = A@W0, out1 = A@W1 (A read once)
__global__ __launch_bounds__(256, 2) void gemm64_2w(
    const u16* __restrict__ A, const u16* __restrict__ WT0, const u16* __restrict__ WT1,
    u16* __restrict__ out0, u16* __restrict__ out1, int M) {
  __shared__ u16 sO0[64][136];
  __shared__ u16 sO1[64][136];
  const int tid = threadIdx.x;
  const int wave = tid >> 6, lane = tid & 63;
  const int q = lane >> 4, l16 = lane & 15;
  const int m0 = blockIdx.x * 64;
  int arow = m0 + wave * 16 + l16;
  if (arow >= M) arow = M - 1;

  f32x4_t a0[8], a1[8];
#pragma unroll
  for (int b = 0; b < 8; ++b) {
    a0[b] = (f32x4_t){0.f, 0.f, 0.f, 0.f};
    a1[b] = (f32x4_t){0.f, 0.f, 0.f, 0.f};
  }
#pragma unroll 2
  for (int kk = 0; kk < 4; ++kk) {
    bf16x8_t af = *(const bf16x8_t*)(A + (size_t)arow * 128 + kk * 32 + q * 8);
#pragma unroll
    for (int nt = 0; nt < 8; ++nt) {
      bf16x8_t b0 = *(const bf16x8_t*)(WT0 + (size_t)(nt * 16 + l16) * 128 + kk * 32 + q * 8);
      bf16x8_t b1v = *(const bf16x8_t*)(WT1 + (size_t)(nt * 16 + l16) * 128 + kk * 32 + q * 8);
      a0[nt] = __builtin_amdgcn_mfma_f32_16x16x32_bf16(af, b0, a0[nt], 0, 0, 0);
      a1[nt] = __builtin_amdgcn_mfma_f32_16x16x32_bf16(af, b1v, a1[nt], 0, 0, 0);
    }
  }
  const int rowb = wave * 16 + q * 4;
#pragma unroll
  for (int r = 0; r < 4; ++r)
#pragma unroll
    for (int nt = 0; nt < 8; ++nt) {
      sO0[rowb + r][nt * 16 + l16] = fb(a0[nt][r]);
      sO1[rowb + r][nt * 16 + l16] = fb(a1[nt][r]);
    }
  __syncthreads();
#pragma unroll
  for (int it = 0; it < 4; ++it) {
    int lin = it * 256 + tid;
    int row = lin >> 4, ch = (lin & 15) * 8;
    int grow = m0 + row;
    if (grow >= M) continue;
    *(uint4*)(out0 + (size_t)grow * 128 + ch) = *(uint4*)(&sO0[row][ch]);
    *(uint4*)(out1 + (size_t)grow * 128 + ch) = *(uint4*)(&sO1[row][ch]);
  }
}

// ---------------- fused edge kernel ----------------
// CSR=true: edges receiver-sorted, msg row e -> msgbuf[e]; else atomic scatter.
template <bool CSR>
__global__ __launch_bounds__(256, 2) void edge_fused(
    u16* __restrict__ eh, const u16* __restrict__ xhA, const u16* __restrict__ xhB,
    const u16* __restrict__ wtC, const float* __restrict__ b1, const u16* __restrict__ wt2,
    const float* __restrict__ b2, const float* __restrict__ gg, const float* __restrict__ bb,
    const int* __restrict__ sArr, const int* __restrict__ rArr, u16* __restrict__ msgbuf,
    float* __restrict__ scat, int E) {
  __shared__ u16 sHm[64][136];
  __shared__ u16 sHe[64][136];
  __shared__ int sS[64], sR[64];
  const int tid = threadIdx.x;
  const int wave = tid >> 6, lane = tid & 63;
  const int q = lane >> 4, l16 = lane & 15;
  const int m0 = blockIdx.x * 64;
  const int rowb = wave * 16 + q * 4;
  int arow = m0 + wave * 16 + l16;
  int arc = arow < E ? arow : E - 1;

  if (tid < 64) {
    int e = m0 + tid;
    sS[tid] = (e < E) ? sArr[e] : 0;
    sR[tid] = (e < E) ? rArr[e] : 0;
  }

  // phase 1: T = eh @ WC
  f32x4_t accC[8];
#pragma unroll
  for (int b = 0; b < 8; ++b) accC[b] = (f32x4_t){0.f, 0.f, 0.f, 0.f};
#pragma unroll
  for (int kk = 0; kk < 4; ++kk) {
    bf16x8_t af = *(const bf16x8_t*)(eh + (size_t)arc * 128 + kk * 32 + q * 8);
#pragma unroll
    for (int nt = 0; nt < 8; ++nt) {
      bf16x8_t bfv = *(const bf16x8_t*)(wtC + (size_t)(nt * 16 + l16) * 128 + kk * 32 + q * 8);
      accC[nt] = __builtin_amdgcn_mfma_f32_16x16x32_bf16(af, bfv, accC[nt], 0, 0, 0);
    }
  }
  // T -> sHm (C-layout)
#pragma unroll
  for (int r = 0; r < 4; ++r)
#pragma unroll
    for (int nt = 0; nt < 8; ++nt) sHm[rowb + r][nt * 16 + l16] = fb(accC[nt][r]);
  __syncthreads();

  // phase 2: row-wise vectorized gather + ReLU; sHm <- H_msg, sHe <- H_edge
#pragma unroll
  for (int it = 0; it < 4; ++it) {
    int lin = it * 256 + tid;
    int row = lin >> 4, ch = (lin & 15) * 8;
    bool ok = (m0 + row) < E;
    int s_ = sS[row], r_ = sR[row];
    u16 t8[8], ar[8], as_[8], br[8], bs[8], hm[8], he[8];
    *(uint4*)t8 = *(uint4*)(&sHm[row][ch]);
    *(uint4*)ar = *(const uint4*)(xhA + (size_t)r_ * 128 + ch);
    *(uint4*)as_ = *(const uint4*)(xhA + (size_t)s_ * 128 + ch);
    *(uint4*)br = *(const uint4*)(xhB + (size_t)r_ * 128 + ch);
    *(uint4*)bs = *(const uint4*)(xhB + (size_t)s_ * 128 + ch);
#pragma unroll
    for (int j = 0; j < 8; ++j) {
      float t = bl(t8[j]) + b1[ch + j];
      float vm = t + bl(ar[j]) + bl(bs[j]);
      float ve = t + bl(as_[j]) + bl(br[j]);
      hm[j] = (ok && vm > 0.f) ? fb(vm) : 0;
      he[j] = (ok && ve > 0.f) ? fb(ve) : 0;
    }
    *(uint4*)(&sHm[row][ch]) = *(uint4*)hm;
    *(uint4*)(&sHe[row][ch]) = *(uint4*)he;
  }
  __syncthreads();

  float bcol[8], gcol[8], becol[8];
#pragma unroll
  for (int nt = 0; nt < 8; ++nt) {
    bcol[nt] = b2[nt * 16 + l16];
    gcol[nt] = gg[nt * 16 + l16];
    becol[nt] = bb[nt * 16 + l16];
  }

  // phase 3: both GEMMs back-to-back, then LN stats
  f32x4_t accM[8], accE[8];
#pragma unroll
  for (int b = 0; b < 8; ++b) {
    accM[b] = (f32x4_t){0.f, 0.f, 0.f, 0.f};
    accE[b] = (f32x4_t){0.f, 0.f, 0.f, 0.f};
  }
#pragma unroll
  for (int kk = 0; kk < 4; ++kk) {
    bf16x8_t afm = *(const bf16x8_t*)(&sHm[wave * 16 + l16][kk * 32 + q * 8]);
    bf16x8_t afe = *(const bf16x8_t*)(&sHe[wave * 16 + l16][kk * 32 + q * 8]);
#pragma unroll
    for (int nt = 0; nt < 8; ++nt) {
      bf16x8_t bfv = *(const bf16x8_t*)(wt2 + (size_t)(nt * 16 + l16) * 128 + kk * 32 + q * 8);
      accM[nt] = __builtin_amdgcn_mfma_f32_16x16x32_bf16(afm, bfv, accM[nt], 0, 0, 0);
      accE[nt] = __builtin_amdgcn_mfma_f32_16x16x32_bf16(afe, bfv, accE[nt], 0, 0, 0);
    }
  }
  float sm[4] = {0, 0, 0, 0}, ssm[4] = {0, 0, 0, 0};
  float se[4] = {0, 0, 0, 0}, sse[4] = {0, 0, 0, 0};
#pragma unroll
  for (int r = 0; r < 4; ++r)
#pragma unroll
    for (int nt = 0; nt < 8; ++nt) {
      float vm = accM[nt][r] + bcol[nt];
      float ve = accE[nt][r] + bcol[nt];
      sm[r] += vm; ssm[r] += vm * vm;
      se[r] += ve; sse[r] += ve * ve;
    }
#pragma unroll
  for (int r = 0; r < 4; ++r) {
#pragma unroll
    for (int m = 1; m <= 8; m <<= 1) {
      sm[r] += __shfl_xor(sm[r], m, 64);
      ssm[r] += __shfl_xor(ssm[r], m, 64);
      se[r] += __shfl_xor(se[r], m, 64);
      sse[r] += __shfl_xor(sse[r], m, 64);
    }
  }

  if (!CSR) {
#pragma unroll
    for (int r = 0; r < 4; ++r) {
      int row = m0 + rowb + r;
      if (row >= E) continue;
      int rr = sR[rowb + r];
      float mean = sm[r] * (1.f / 128.f);
      float var = fmaxf(ssm[r] * (1.f / 128.f) - mean * mean, 0.f);
      float rstd = rsqrtf(var + 1e-5f);
#pragma unroll
      for (int nt = 0; nt < 8; ++nt) {
        float v = (accM[nt][r] + bcol[nt] - mean) * rstd * gcol[nt] + becol[nt];
        atomicAdd(&scat[(size_t)rr * 128 + nt * 16 + l16], v);
      }
    }
  }

  __syncthreads();  // all LDS reads done; safe to overwrite
#pragma unroll
  for (int r = 0; r < 4; ++r) {
    float meanE = se[r] * (1.f / 128.f);
    float varE = fmaxf(sse[r] * (1.f / 128.f) - meanE * meanE, 0.f);
    float rstdE = rsqrtf(varE + 1e-5f);
    float meanM = sm[r] * (1.f / 128.f);
    float varM = fmaxf(ssm[r] * (1.f / 128.f) - meanM * meanM, 0.f);
    float rstdM = rsqrtf(varM + 1e-5f);
#pragma unroll
    for (int nt = 0; nt < 8; ++nt) {
      float ve = (accE[nt][r] + bcol[nt] - meanE) * rstdE * gcol[nt] + becol[nt];
      sHe[rowb + r][nt * 16 + l16] = fb(ve);
      if (CSR) {
        float vm = (accM[nt][r] + bcol[nt] - meanM) * rstdM * gcol[nt] + becol[nt];
        sHm[rowb + r][nt * 16 + l16] = fb(vm);
      }
    }
  }
  __syncthreads();
  // row-wise vector stores: msg -> msgbuf[row] (sequential), Ye+eh -> eh
#pragma unroll
  for (int it = 0; it < 4; ++it) {
    int lin = it * 256 + tid;
    int row = lin >> 4, ch = (lin & 15) * 8;
    int grow = m0 + row;
    if (grow >= E) continue;
    if (CSR) {
      *(uint4*)(msgbuf + (size_t)grow * 128 + ch) = *(uint4*)(&sHm[row][ch]);
    }
    u16 y8[8], e8[8];
    *(uint4*)y8 = *(uint4*)(&sHe[row][ch]);
    *(uint4*)e8 = *(const uint4*)(eh + (size_t)grow * 128 + ch);
#pragma unroll
    for (int j = 0; j < 8; ++j) y8[j] = fb(bl(y8[j]) + bl(e8[j]));
    *(uint4*)(eh + (size_t)grow * 128 + ch) = *(uint4*)y8;
  }
}

// decoder: wave per node, 128->64 swish -> 64->5, times dt
__global__ void decoder_kernel(const u16* __restrict__ xh, const float* __restrict__ w1,
                               const float* __restrict__ b1, const float* __restrict__ w2,
                               const float* __restrict__ b2, float* __restrict__ out,
                               int n_nodes) {
  __shared__ float sx[4][128];
  int tid = threadIdx.x;
  int lw = tid >> 6, lane = tid & 63;
  int n0 = blockIdx.x * 4;
  for (int i = tid; i < 512; i += 256) {
    int nn = i >> 7, c = i & 127;
    int n = n0 + nn;
    sx[nn][c] = (n < n_nodes) ? bl(xh[(size_t)n * 128 + c]) : 0.f;
  }
  __syncthreads();
  int n = n0 + lw;
  float h = b1[lane];
#pragma unroll 16
  for (int k = 0; k < 128; ++k) h += sx[lw][k] * w1[k * 64 + lane];
  float hs = h * (1.f / (1.f + __expf(-h)));
  float d[5];
#pragma unroll
  for (int t = 0; t < 5; ++t) {
    float p = hs * w2[lane * 5 + t];
#pragma unroll
    for (int m = 1; m <= 32; m <<= 1) p += __shfl_xor(p, m, 64);
    d[t] = p;
  }
  if (lane == 0 && n < n_nodes) {
#pragma unroll
    for (int t = 0; t < 5; ++t)
      out[(size_t)n * 5 + t] = (float)(t + 1) * (d[t] + b2[t]);
  }
}

extern "C" void kernel_launch(void* const* d_in, const int* in_sizes, int n_in, void* d_out,
                              int out_size, void* d_ws, size_t ws_size, hipStream_t stream) {
  auto F = [&](int i) { return (const float*)d_in[i]; };
  const int* edge_index = (const int*)d_in[6];
  const int N_ = in_sizes[0];
  const int E_ = in_sizes[6] / 2;

  char* wsb = (char*)d_ws;
  size_t off = 0;
  auto alloc = [&](size_t bytes) -> char* {
    char* p = wsb + off;
    off += (bytes + 255) & ~(size_t)255;
    return p;
  };
  u16* xh = (u16*)alloc((size_t)N_ * 128 * 2);
  u16* xhA = (u16*)alloc((size_t)N_ * 128 * 2);
  u16* xhB = (u16*)alloc((size_t)N_ * 128 * 2);
  u16* h1n = (u16*)alloc((size_t)N_ * 128 * 2);
  u16* ehP = (u16*)alloc((size_t)E_ * 128 * 2);
  float* nfeat = (float*)xhA;  // alias (dead before xhA live)
  float* efeat = (float*)xhB;  // alias
  u16* aggrb = xhA;            // alias (xhA dead after edge_fused)
  u16* wne2T = (u16*)alloc(16384 * 2);
  u16* wee2T = (u16*)alloc(16384 * 2);
  u16* wpe1T = (u16*)alloc((size_t)9 * 16384 * 2);
  u16* wpe2T = (u16*)alloc((size_t)3 * 16384 * 2);
  u16* wpn1T = (u16*)alloc((size_t)6 * 16384 * 2);
  u16* wpn2T = (u16*)alloc((size_t)3 * 16384 * 2);

  const size_t base_off = off;
  // CSR-path extras
  int* startp = (int*)alloc((size_t)(N_ + 1) * 4);
  int* cntp = (int*)alloc((size_t)N_ * 4);
  int* partp = (int*)alloc((size_t)N_ * 4);
  int* bsump = (int*)alloc(((size_t)(N_ + 255) / 256) * 4 + 256);
  int* sortedS = (int*)alloc((size_t)E_ * 4);
  int* sortedR = (int*)alloc((size_t)E_ * 4);
  u16* msgbuf = (u16*)alloc((size_t)E_ * 128 * 2);
  bool useCSR = (off <= ws_size);
  float* aggrf = nullptr;
  if (!useCSR) {
    off = base_off;
    aggrf = (float*)alloc((size_t)N_ * 128 * 4);
    if (off > ws_size) {
      sentinel_kernel<<<(out_size + 255) / 256, 256, 0, stream>>>((float*)d_out, out_size);
      return;
    }
  }

  TArgs ta;
  int ts = 0;
  ta.s[ts++] = {F(13), wne2T};
  ta.s[ts++] = {F(19), wee2T};
  for (int i = 0; i < 3; ++i)
    for (int b = 0; b < 3; ++b)
      ta.s[ts++] = {F(23) + (size_t)(i * 3 + b) * 16384, wpe1T + (size_t)(i * 3 + b) * 16384};
  for (int i = 0; i < 3; ++i) ta.s[ts++] = {F(25) + (size_t)i * 16384, wpe2T + (size_t)i * 16384};
  for (int i = 0; i < 3; ++i)
    for (int b = 0; b < 2; ++b)
      ta.s[ts++] = {F(29) + (size_t)(i * 2 + b) * 16384, wpn1T + (size_t)(i * 2 + b) * 16384};
  for (int i = 0; i < 3; ++i) ta.s[ts++] = {F(31) + (size_t)i * 16384, wpn2T + (size_t)i * 16384};

  const int tilesN = (N_ + 63) / 64;
  const int tilesE = (E_ + 63) / 64;
  const int nb = (N_ + 255) / 256;
  dim3 blk(256);

  transpose_w<<<23, blk, 0, stream>>>(ta);

  const int* sArr = edge_index;
  const int* rArr = edge_index + E_;
  if (useCSR) {
    zero_i32<<<(N_ + 255) / 256, blk, 0, stream>>>(cntp, N_);
    deg_count<<<(E_ + 255) / 256, blk, 0, stream>>>(edge_index, cntp, E_);
    scan1<<<nb, blk, 0, stream>>>(cntp, partp, bsump, N_);
    scan2<<<1, blk, 0, stream>>>(bsump, nb);
    scan3<<<nb, blk, 0, stream>>>(partp, bsump, startp, N_);
    zero_i32<<<(N_ + 255) / 256, blk, 0, stream>>>(cntp, N_);
    fill_slot<<<(E_ + 255) / 256, blk, 0, stream>>>(edge_index, cntp, startp, sortedS, sortedR,
                                                    E_);
    sArr = sortedS;
    rArr = sortedR;
  }

  // ---- encode ----
  node_feat_kernel<<<(N_ + 255) / 256, blk, 0, stream>>>(F(0), F(1), F(2), F(3), F(4), F(7),
                                                         F(8), nfeat, N_);
  enc1_kernel<9><<<(N_ * 128 + 255) / 256, blk, 0, stream>>>(nfeat, F(11), F(12), h1n, N_);
  gemm64<GM_LN, false, false><<<tilesN, blk, 0, stream>>>(h1n, wne2T, nullptr, nullptr, F(14),
                                                          F(15), F(16), nullptr, xh, N_);
  edge_feat_kernel<<<(E_ + 255) / 256, blk, 0, stream>>>(sArr, rArr, F(5), F(0), F(9), F(10),
                                                         efeat, E_);
  enc1_kernel<4><<<(E_ * 128 + 255) / 256, blk, 0, stream>>>(efeat, F(17), F(18), ehP, E_);
  gemm64<GM_LN, false, false><<<tilesE, blk, 0, stream>>>(ehP, wee2T, nullptr, nullptr, F(20),
                                                          F(21), F(22), nullptr, ehP, E_);

  // ---- process steps ----
  for (int i = 0; i < 3; ++i) {
    const u16* wtA = wpe1T + (size_t)(i * 3 + 0) * 16384;
    const u16* wtB = wpe1T + (size_t)(i * 3 + 1) * 16384;
    const u16* wtC = wpe1T + (size_t)(i * 3 + 2) * 16384;
    const float* pb1 = F(24) + i * 128;
    const u16* wt2 = wpe2T + (size_t)i * 16384;
    const float* pb2 = F(26) + i * 128;
    const float* pg = F(27) + i * 128;
    const float* pbe = F(28) + i * 128;
    const u16* wtnA = wpn1T + (size_t)(i * 2 + 0) * 16384;
    const u16* wtnB = wpn1T + (size_t)(i * 2 + 1) * 16384;
    const float* nb1 = F(30) + i * 128;
    const u16* wtn2 = wpn2T + (size_t)i * 16384;
    const float* nb2 = F(32) + i * 128;
    const float* ng = F(33) + i * 128;
    const float* nbe = F(34) + i * 128;

    gemm64_2w<<<tilesN, blk, 0, stream>>>(xh, wtA, wtB, xhA, xhB, N_);
    if (useCSR) {
      edge_fused<true><<<tilesE, blk, 0, stream>>>(ehP, xhA, xhB, wtC, pb1, wt2, pb2, pg, pbe,
                                                   sArr, rArr, msgbuf, nullptr, E_);
      aggregate<<<(N_ + 15) / 16, blk, 0, stream>>>(msgbuf, startp, aggrb, N_);
      gemm64<GM_RELU, true, false><<<tilesN, blk, 0, stream>>>(aggrb, wtnA, xh, wtnB, nb1,
                                                               nullptr, nullptr, nullptr, h1n,
                                                               N_);
    } else {
      (void)hipMemsetAsync(aggrf, 0, (size_t)N_ * 128 * 4, stream);
      edge_fused<false><<<tilesE, blk, 0, stream>>>(ehP, xhA, xhB, wtC, pb1, wt2, pb2, pg, pbe,
                                                    sArr, rArr, nullptr, aggrf, E_);
      gemm64<GM_RELU, true, true><<<tilesN, blk, 0, stream>>>(aggrf, wtnA, xh, wtnB, nb1,
                                                              nullptr, nullptr, nullptr, h1n,
                                                              N_);
    }
    gemm64<GM_LN, false, false><<<tilesN, blk, 0, stream>>>(h1n, wtn2, nullptr, nullptr, nb2,
                                                            ng, nbe, xh, xh, N_);
  }

  // ---- decode ----
  decoder_kernel<<<(N_ + 3) / 4, blk, 0, stream>>>(xh, F(35), F(36), F(37), F(38),
                                                   (float*)d_out, N_);
}

// Round 12
// 1347.168 us; speedup vs baseline: 1.4170x; 1.0211x over previous
//
#include <hip/hip_runtime.h>
#include <stdint.h>

typedef unsigned short u16;
typedef __attribute__((ext_vector_type(8))) short bf16x8_t;
typedef __attribute__((ext_vector_type(4))) float f32x4_t;

__device__ __forceinline__ float bl(u16 x) {
  union { unsigned u; float f; } c; c.u = ((unsigned)x) << 16; return c.f;
}
__device__ __forceinline__ u16 fb(float x) {
  union { float f; unsigned u; } c; c.f = x;
  unsigned r = c.u + 0x7fffu + ((c.u >> 16) & 1u);
  return (u16)(r >> 16);
}

__global__ void sentinel_kernel(float* out, int n) {
  int i = blockIdx.x * 256 + threadIdx.x;
  if (i < n) out[i] = 12345.f;
}

// ---------------- weight transpose: wT[n][k] = fb(W[k][n]) ----------------
struct TSeg { const float* src; u16* dst; };
struct TArgs { TSeg s[23]; };
__global__ void transpose_w(TArgs a) {
  const float* src = a.s[blockIdx.x].src;
  u16* dst = a.s[blockIdx.x].dst;
  for (int e = threadIdx.x; e < 16384; e += 256) {
    int n = e >> 7, k = e & 127;
    dst[e] = fb(src[k * 128 + n]);
  }
}

// ---------------- CSR build + receiver-sort ----------------
__global__ void zero_i32(int* p, int n) {
  int i = blockIdx.x * 256 + threadIdx.x;
  if (i < n) p[i] = 0;
}
__global__ void deg_count(const int* __restrict__ ei, int* __restrict__ cnt, int E) {
  int e = blockIdx.x * 256 + threadIdx.x;
  if (e < E) atomicAdd(&cnt[ei[E + e]], 1);
}
__global__ void scan1(const int* __restrict__ cnt, int* __restrict__ part,
                      int* __restrict__ bsum, int N) {
  __shared__ int s[256];
  int i = blockIdx.x * 256 + threadIdx.x;
  s[threadIdx.x] = (i < N) ? cnt[i] : 0;
  __syncthreads();
#pragma unroll
  for (int o = 1; o < 256; o <<= 1) {
    int t = (threadIdx.x >= o) ? s[threadIdx.x - o] : 0;
    __syncthreads();
    s[threadIdx.x] += t;
    __syncthreads();
  }
  if (i < N) part[i] = s[threadIdx.x];
  if (threadIdx.x == 255) bsum[blockIdx.x] = s[255];
}
__global__ void scan2(int* bsum, int nb) {
  if (threadIdx.x == 0 && blockIdx.x == 0) {
    int acc = 0;
    for (int i = 0; i < nb; ++i) { int t = bsum[i]; bsum[i] = acc; acc += t; }
  }
}
__global__ void scan3(const int* __restrict__ part, const int* __restrict__ bsum,
                      int* __restrict__ start, int N) {
  int i = blockIdx.x * 256 + threadIdx.x;
  if (i < N) start[i + 1] = part[i] + bsum[i >> 8];
  if (i == 0) start[0] = 0;
}
__global__ void fill_slot(const int* __restrict__ ei, int* __restrict__ cnt2,
                          const int* __restrict__ start, int* __restrict__ sortedS,
                          int* __restrict__ sortedR, int E) {
  int e = blockIdx.x * 256 + threadIdx.x;
  if (e >= E) return;
  int s = ei[e], r = ei[E + e];
  int p = atomicAdd(&cnt2[r], 1);
  int slot = start[r] + p;
  sortedS[slot] = s;
  sortedR[slot] = r;
}

// ---------------- feature kernels ----------------
__global__ void node_feat_kernel(const float* __restrict__ t, const float* __restrict__ tp,
                                 const float* __restrict__ q, const float* __restrict__ qp,
                                 const float* __restrict__ qn, const float* __restrict__ nm,
                                 const float* __restrict__ ns, float* __restrict__ nfeat,
                                 int n_nodes) {
  int n = blockIdx.x * 256 + threadIdx.x;
  if (n >= n_nodes) return;
  float u = t[n];
  float x[9];
  x[0] = u; x[1] = u - tp[n];
  float hq = q[n];
  x[2] = hq; x[3] = hq - qp[n];
#pragma unroll
  for (int j = 0; j < 5; ++j) x[4 + j] = qn[n * 5 + j];
#pragma unroll
  for (int k = 0; k < 9; ++k) nfeat[n * 9 + k] = (x[k] - nm[k]) / ns[k];
}

__global__ void edge_feat_kernel(const int* __restrict__ sArr, const int* __restrict__ rArr,
                                 const float* __restrict__ mp, const float* __restrict__ u,
                                 const float* __restrict__ em, const float* __restrict__ es,
                                 float* __restrict__ efeat, int n_edges) {
  int e = blockIdx.x * 256 + threadIdx.x;
  if (e >= n_edges) return;
  int s = sArr[e], r = rArr[e];
  float rx = mp[s * 2] - mp[r * 2];
  float ry = mp[s * 2 + 1] - mp[r * 2 + 1];
  float d = sqrtf(rx * rx + ry * ry);
  float rt = u[s] - u[r];
  float x[4] = {rx, ry, d, rt};
#pragma unroll
  for (int k = 0; k < 4; ++k) efeat[e * 4 + k] = (x[k] - em[k]) / es[k];
}

template <int K>
__global__ void enc1_kernel(const float* __restrict__ feat, const float* __restrict__ w1,
                            const float* __restrict__ b1, u16* __restrict__ out, int M) {
  int gid = blockIdx.x * 256 + threadIdx.x;
  int n = gid >> 7, h = gid & 127;
  if (n >= M) return;
  float acc = b1[h];
#pragma unroll
  for (int k = 0; k < K; ++k) acc += feat[n * K + k] * w1[k * 128 + h];
  out[n * 128 + h] = fb(acc > 0.f ? acc : 0.f);
}

// ---------------- LDS-free-GEMM + LDS-staged vector-store epilogue ----------------
#define GM_NONE 0
#define GM_RELU 1
#define GM_LN 2

template <int MODE, bool DUAL, bool A0F32>
__global__ __launch_bounds__(256, 2) void gemm64(
    const void* __restrict__ A0v, const u16* __restrict__ WT0, const u16* __restrict__ A1,
    const u16* __restrict__ WT1, const float* __restrict__ bias, const float* __restrict__ gg,
    const float* __restrict__ bb, const u16* __restrict__ resid, u16* __restrict__ out, int M) {
  __shared__ u16 sO[64][136];
  const int tid = threadIdx.x;
  const int wave = tid >> 6, lane = tid & 63;
  const int q = lane >> 4, l16 = lane & 15;
  const int m0 = blockIdx.x * 64;
  int arow = m0 + wave * 16 + l16;
  if (arow >= M) arow = M - 1;

  f32x4_t acc[8];
#pragma unroll
  for (int b = 0; b < 8; ++b) acc[b] = (f32x4_t){0.f, 0.f, 0.f, 0.f};

  const int NKT = DUAL ? 2 : 1;
#pragma unroll 1
  for (int kt = 0; kt < NKT; ++kt) {
    const u16* WT = kt ? WT1 : WT0;
#pragma unroll
    for (int kk = 0; kk < 4; ++kk) {
      bf16x8_t af;
      if (A0F32 && kt == 0) {
        const float* ap = (const float*)A0v + (size_t)arow * 128 + kk * 32 + q * 8;
        union { u16 u[8]; bf16x8_t v; } cv;
#pragma unroll
        for (int j = 0; j < 8; ++j) cv.u[j] = fb(ap[j]);
        af = cv.v;
      } else {
        const u16* ap = (kt ? A1 : (const u16*)A0v) + (size_t)arow * 128 + kk * 32 + q * 8;
        af = *(const bf16x8_t*)ap;
      }
      const u16* wp = WT + kk * 32 + q * 8;
#pragma unroll
      for (int nt = 0; nt < 8; ++nt) {
        bf16x8_t bfv = *(const bf16x8_t*)(wp + (size_t)(nt * 16 + l16) * 128);
        acc[nt] = __builtin_amdgcn_mfma_f32_16x16x32_bf16(af, bfv, acc[nt], 0, 0, 0);
      }
    }
  }

  const int rowb = wave * 16 + q * 4;
  if (MODE == GM_NONE) {
#pragma unroll
    for (int r = 0; r < 4; ++r)
#pragma unroll
      for (int nt = 0; nt < 8; ++nt) sO[rowb + r][nt * 16 + l16] = fb(acc[nt][r]);
  } else if (MODE == GM_RELU) {
    float bcol[8];
#pragma unroll
    for (int nt = 0; nt < 8; ++nt) bcol[nt] = bias[nt * 16 + l16];
#pragma unroll
    for (int r = 0; r < 4; ++r)
#pragma unroll
      for (int nt = 0; nt < 8; ++nt) {
        float v = acc[nt][r] + bcol[nt];
        sO[rowb + r][nt * 16 + l16] = fb(v > 0.f ? v : 0.f);
      }
  } else {
    float bcol[8], gcol[8], becol[8];
#pragma unroll
    for (int nt = 0; nt < 8; ++nt) {
      bcol[nt] = bias[nt * 16 + l16];
      gcol[nt] = gg[nt * 16 + l16];
      becol[nt] = bb[nt * 16 + l16];
    }
    float s[4] = {0, 0, 0, 0}, ss[4] = {0, 0, 0, 0};
#pragma unroll
    for (int r = 0; r < 4; ++r)
#pragma unroll
      for (int nt = 0; nt < 8; ++nt) {
        float v = acc[nt][r] + bcol[nt];
        s[r] += v;
        ss[r] += v * v;
      }
#pragma unroll
    for (int r = 0; r < 4; ++r) {
#pragma unroll
      for (int m = 1; m <= 8; m <<= 1) {
        s[r] += __shfl_xor(s[r], m, 64);
        ss[r] += __shfl_xor(ss[r], m, 64);
      }
    }
#pragma unroll
    for (int r = 0; r < 4; ++r) {
      float mean = s[r] * (1.f / 128.f);
      float var = fmaxf(ss[r] * (1.f / 128.f) - mean * mean, 0.f);
      float rstd = rsqrtf(var + 1e-5f);
#pragma unroll
      for (int nt = 0; nt < 8; ++nt) {
        float v = (acc[nt][r] + bcol[nt] - mean) * rstd * gcol[nt] + becol[nt];
        sO[rowb + r][nt * 16 + l16] = fb(v);
      }
    }
  }
  __syncthreads();
#pragma unroll
  for (int it = 0; it < 4; ++it) {
    int lin = it * 256 + tid;
    int row = lin >> 4, ch = (lin & 15) * 8;
    int grow = m0 + row;
    if (grow >= M) continue;
    u16 o8[8];
    *(uint4*)o8 = *(uint4*)(&sO[row][ch]);
    if (MODE == GM_LN && resid) {
      u16 r8[8];
      *(uint4*)r8 = *(const uint4*)(resid + (size_t)grow * 128 + ch);
#pragma unroll
      for (int j = 0; j < 8; ++j) o8[j] = fb(bl(o8[j]) + bl(r8[j]));
    }
    *(uint4*)(out + (size_t)grow * 128 + ch) = *(uint4*)o8;
  }
}

// dual-output GEMM: out0 = A@W0, out1 = A@W1 (A read once)
__global__ __launch_bounds__(256, 2) void gemm64_2w(
    const u16* __restrict__ A, const u16* __restrict__ WT0, const u16* __restrict__ WT1,
    u16* __restrict__ out0, u16* __restrict__ out1, int M) {
  __shared__ u16 sO0[64][136];
  __shared__ u16 sO1[64][136];
  const int tid = threadIdx.x;
  const int wave = tid >> 6, lane = tid & 63;
  const int q = lane >> 4, l16 = lane & 15;
  const int m0 = blockIdx.x * 64;
  int arow = m0 + wave * 16 + l16;
  if (arow >= M) arow = M - 1;

  f32x4_t a0[8], a1[8];
#pragma unroll
  for (int b = 0; b < 8; ++b) {
    a0[b] = (f32x4_t){0.f, 0.f, 0.f, 0.f};
    a1[b] = (f32x4_t){0.f, 0.f, 0.f, 0.f};
  }
#pragma unroll 2
  for (int kk = 0; kk < 4; ++kk) {
    bf16x8_t af = *(const bf16x8_t*)(A + (size_t)arow * 128 + kk * 32 + q * 8);
#pragma unroll
    for (int nt = 0; nt < 8; ++nt) {
      bf16x8_t b0 = *(const bf16x8_t*)(WT0 + (size_t)(nt * 16 + l16) * 128 + kk * 32 + q * 8);
      bf16x8_t b1v = *(const bf16x8_t*)(WT1 + (size_t)(nt * 16 + l16) * 128 + kk * 32 + q * 8);
      a0[nt] = __builtin_amdgcn_mfma_f32_16x16x32_bf16(af, b0, a0[nt], 0, 0, 0);
      a1[nt] = __builtin_amdgcn_mfma_f32_16x16x32_bf16(af, b1v, a1[nt], 0, 0, 0);
    }
  }
  const int rowb = wave * 16 + q * 4;
#pragma unroll
  for (int r = 0; r < 4; ++r)
#pragma unroll
    for (int nt = 0; nt < 8; ++nt) {
      sO0[rowb + r][nt * 16 + l16] = fb(a0[nt][r]);
      sO1[rowb + r][nt * 16 + l16] = fb(a1[nt][r]);
    }
  __syncthreads();
#pragma unroll
  for (int it = 0; it < 4; ++it) {
    int lin = it * 256 + tid;
    int row = lin >> 4, ch = (lin & 15) * 8;
    int grow = m0 + row;
    if (grow >= M) continue;
    *(uint4*)(out0 + (size_t)grow * 128 + ch) = *(uint4*)(&sO0[row][ch]);
    *(uint4*)(out1 + (size_t)grow * 128 + ch) = *(uint4*)(&sO1[row][ch]);
  }
}

// ---------------- fused edge kernel ----------------
// CSR=true: receiver-sorted edges; in-kernel segmented aggregation into aggr (f32).
// CSR=false: atomic scatter of every message row into aggr.
template <bool CSR>
__global__ __launch_bounds__(256, 2) void edge_fused(
    u16* __restrict__ eh, const u16* __restrict__ xhA, const u16* __restrict__ xhB,
    const u16* __restrict__ wtC, const float* __restrict__ b1, const u16* __restrict__ wt2,
    const float* __restrict__ b2, const float* __restrict__ gg, const float* __restrict__ bb,
    const int* __restrict__ sArr, const int* __restrict__ rArr,
    const int* __restrict__ startp, float* __restrict__ aggr, int E) {
  __shared__ u16 sHm[64][136];
  __shared__ u16 sHe[64][136];
  __shared__ int sR[64];
  const int tid = threadIdx.x;
  const int wave = tid >> 6, lane = tid & 63;
  const int q = lane >> 4, l16 = lane & 15;
  const int m0 = blockIdx.x * 64;
  const int rowb = wave * 16 + q * 4;
  int arow = m0 + wave * 16 + l16;
  int arc = arow < E ? arow : E - 1;

  if (tid < 64) {
    int e = m0 + tid;
    sR[tid] = (e < E) ? rArr[e] : -1;
  }

  // prefetch sender gather rows (random-latency; independent of T GEMM)
  int prow[4], pch[4], pr_[4];
  uint4 pAs[4], pBs[4];
#pragma unroll
  for (int it = 0; it < 4; ++it) {
    int lin = it * 256 + tid;
    prow[it] = lin >> 4;
    pch[it] = (lin & 15) * 8;
    int ge = m0 + prow[it];
    int gc = ge < E ? ge : E - 1;
    int ps = sArr[gc];
    pr_[it] = rArr[gc];
    pAs[it] = *(const uint4*)(xhA + (size_t)ps * 128 + pch[it]);
    pBs[it] = *(const uint4*)(xhB + (size_t)ps * 128 + pch[it]);
  }

  // phase 1: T = eh @ WC
  f32x4_t accC[8];
#pragma unroll
  for (int b = 0; b < 8; ++b) accC[b] = (f32x4_t){0.f, 0.f, 0.f, 0.f};
#pragma unroll
  for (int kk = 0; kk < 4; ++kk) {
    bf16x8_t af = *(const bf16x8_t*)(eh + (size_t)arc * 128 + kk * 32 + q * 8);
#pragma unroll
    for (int nt = 0; nt < 8; ++nt) {
      bf16x8_t bfv = *(const bf16x8_t*)(wtC + (size_t)(nt * 16 + l16) * 128 + kk * 32 + q * 8);
      accC[nt] = __builtin_amdgcn_mfma_f32_16x16x32_bf16(af, bfv, accC[nt], 0, 0, 0);
    }
  }
#pragma unroll
  for (int r = 0; r < 4; ++r)
#pragma unroll
    for (int nt = 0; nt < 8; ++nt) sHm[rowb + r][nt * 16 + l16] = fb(accC[nt][r]);
  __syncthreads();

  // phase 2: receiver rows (sorted -> cache-friendly) + prefetched sender rows
#pragma unroll
  for (int it = 0; it < 4; ++it) {
    int row = prow[it], ch = pch[it];
    bool ok = (m0 + row) < E;
    int r_ = pr_[it] >= 0 ? pr_[it] : 0;
    u16 t8[8], ar[8], as_[8], br[8], bs[8], hm[8], he[8];
    *(uint4*)t8 = *(uint4*)(&sHm[row][ch]);
    *(uint4*)ar = *(const uint4*)(xhA + (size_t)r_ * 128 + ch);
    *(uint4*)br = *(const uint4*)(xhB + (size_t)r_ * 128 + ch);
    *(uint4*)as_ = pAs[it];
    *(uint4*)bs = pBs[it];
#pragma unroll
    for (int j = 0; j < 8; ++j) {
      float t = bl(t8[j]) + b1[ch + j];
      float vm = t + bl(ar[j]) + bl(bs[j]);
      float ve = t + bl(as_[j]) + bl(br[j]);
      hm[j] = (ok && vm > 0.f) ? fb(vm) : 0;
      he[j] = (ok && ve > 0.f) ? fb(ve) : 0;
    }
    *(uint4*)(&sHm[row][ch]) = *(uint4*)hm;
    *(uint4*)(&sHe[row][ch]) = *(uint4*)he;
  }
  __syncthreads();

  float bcol[8], gcol[8], becol[8];
#pragma unroll
  for (int nt = 0; nt < 8; ++nt) {
    bcol[nt] = b2[nt * 16 + l16];
    gcol[nt] = gg[nt * 16 + l16];
    becol[nt] = bb[nt * 16 + l16];
  }

  // phase 3: both GEMMs back-to-back, then LN stats
  f32x4_t accM[8], accE[8];
#pragma unroll
  for (int b = 0; b < 8; ++b) {
    accM[b] = (f32x4_t){0.f, 0.f, 0.f, 0.f};
    accE[b] = (f32x4_t){0.f, 0.f, 0.f, 0.f};
  }
#pragma unroll
  for (int kk = 0; kk < 4; ++kk) {
    bf16x8_t afm = *(const bf16x8_t*)(&sHm[wave * 16 + l16][kk * 32 + q * 8]);
    bf16x8_t afe = *(const bf16x8_t*)(&sHe[wave * 16 + l16][kk * 32 + q * 8]);
#pragma unroll
    for (int nt = 0; nt < 8; ++nt) {
      bf16x8_t bfv = *(const bf16x8_t*)(wt2 + (size_t)(nt * 16 + l16) * 128 + kk * 32 + q * 8);
      accM[nt] = __builtin_amdgcn_mfma_f32_16x16x32_bf16(afm, bfv, accM[nt], 0, 0, 0);
      accE[nt] = __builtin_amdgcn_mfma_f32_16x16x32_bf16(afe, bfv, accE[nt], 0, 0, 0);
    }
  }
  float sm[4] = {0, 0, 0, 0}, ssm[4] = {0, 0, 0, 0};
  float se[4] = {0, 0, 0, 0}, sse[4] = {0, 0, 0, 0};
#pragma unroll
  for (int r = 0; r < 4; ++r)
#pragma unroll
    for (int nt = 0; nt < 8; ++nt) {
      float vm = accM[nt][r] + bcol[nt];
      float ve = accE[nt][r] + bcol[nt];
      sm[r] += vm; ssm[r] += vm * vm;
      se[r] += ve; sse[r] += ve * ve;
    }
#pragma unroll
  for (int r = 0; r < 4; ++r) {
#pragma unroll
    for (int m = 1; m <= 8; m <<= 1) {
      sm[r] += __shfl_xor(sm[r], m, 64);
      ssm[r] += __shfl_xor(ssm[r], m, 64);
      se[r] += __shfl_xor(se[r], m, 64);
      sse[r] += __shfl_xor(sse[r], m, 64);
    }
  }

  if (!CSR) {
#pragma unroll
    for (int r = 0; r < 4; ++r) {
      int row = m0 + rowb + r;
      if (row >= E) continue;
      int rr = sR[rowb + r];
      float mean = sm[r] * (1.f / 128.f);
      float var = fmaxf(ssm[r] * (1.f / 128.f) - mean * mean, 0.f);
      float rstd = rsqrtf(var + 1e-5f);
#pragma unroll
      for (int nt = 0; nt < 8; ++nt) {
        float v = (accM[nt][r] + bcol[nt] - mean) * rstd * gcol[nt] + becol[nt];
        atomicAdd(&aggr[(size_t)rr * 128 + nt * 16 + l16], v);
      }
    }
  }

  __syncthreads();  // all LDS reads done; safe to overwrite
#pragma unroll
  for (int r = 0; r < 4; ++r) {
    float meanE = se[r] * (1.f / 128.f);
    float varE = fmaxf(sse[r] * (1.f / 128.f) - meanE * meanE, 0.f);
    float rstdE = rsqrtf(varE + 1e-5f);
    float meanM = sm[r] * (1.f / 128.f);
    float varM = fmaxf(ssm[r] * (1.f / 128.f) - meanM * meanM, 0.f);
    float rstdM = rsqrtf(varM + 1e-5f);
#pragma unroll
    for (int nt = 0; nt < 8; ++nt) {
      float ve = (accE[nt][r] + bcol[nt] - meanE) * rstdE * gcol[nt] + becol[nt];
      sHe[rowb + r][nt * 16 + l16] = fb(ve);
      if (CSR) {
        float vm = (accM[nt][r] + bcol[nt] - meanM) * rstdM * gcol[nt] + becol[nt];
        sHm[rowb + r][nt * 16 + l16] = fb(vm);
      }
    }
  }
  __syncthreads();

  // epilogue: eh residual+store; CSR: segmented aggregation of Ym rows
#pragma unroll
  for (int it = 0; it < 4; ++it) {
    int row = prow[it], ch = pch[it];
    int grow = m0 + row;
    if (grow >= E) continue;
    u16 y8[8], e8[8];
    *(uint4*)y8 = *(uint4*)(&sHe[row][ch]);
    *(uint4*)e8 = *(const uint4*)(eh + (size_t)grow * 128 + ch);
#pragma unroll
    for (int j = 0; j < 8; ++j) y8[j] = fb(bl(y8[j]) + bl(e8[j]));
    *(uint4*)(eh + (size_t)grow * 128 + ch) = *(uint4*)y8;

    if (CSR) {
      int rr = sR[row];
      bool first = (row == 0) || (sR[row - 1] != rr);
      if (!first) continue;
      int gs = startp[rr], ge2 = startp[rr + 1];
      int le = ge2 - m0;
      if (le > 64) le = 64;
      float acc[8] = {0, 0, 0, 0, 0, 0, 0, 0};
      for (int i = row; i < le; ++i) {
        u16 m8[8];
        *(uint4*)m8 = *(uint4*)(&sHm[i][ch]);
#pragma unroll
        for (int j = 0; j < 8; ++j) acc[j] += bl(m8[j]);
      }
      if (gs >= m0 && ge2 <= m0 + 64) {
        *(float4*)(aggr + (size_t)rr * 128 + ch) = make_float4(acc[0], acc[1], acc[2], acc[3]);
        *(float4*)(aggr + (size_t)rr * 128 + ch + 4) =
            make_float4(acc[4], acc[5], acc[6], acc[7]);
      } else {
#pragma unroll
        for (int j = 0; j < 8; ++j) atomicAdd(&aggr[(size_t)rr * 128 + ch + j], acc[j]);
      }
    }
  }
}

// decoder: wave per node, 128->64 swish -> 64->5, times dt
__global__ void decoder_kernel(const u16* __restrict__ xh, const float* __restrict__ w1,
                               const float* __restrict__ b1, const float* __restrict__ w2,
                               const float* __restrict__ b2, float* __restrict__ out,
                               int n_nodes) {
  __shared__ float sx[4][128];
  int tid = threadIdx.x;
  int lw = tid >> 6, lane = tid & 63;
  int n0 = blockIdx.x * 4;
  for (int i = tid; i < 512; i += 256) {
    int nn = i >> 7, c = i & 127;
    int n = n0 + nn;
    sx[nn][c] = (n < n_nodes) ? bl(xh[(size_t)n * 128 + c]) : 0.f;
  }
  __syncthreads();
  int n = n0 + lw;
  float h = b1[lane];
#pragma unroll 16
  for (int k = 0; k < 128; ++k) h += sx[lw][k] * w1[k * 64 + lane];
  float hs = h * (1.f / (1.f + __expf(-h)));
  float d[5];
#pragma unroll
  for (int t = 0; t < 5; ++t) {
    float p = hs * w2[lane * 5 + t];
#pragma unroll
    for (int m = 1; m <= 32; m <<= 1) p += __shfl_xor(p, m, 64);
    d[t] = p;
  }
  if (lane == 0 && n < n_nodes) {
#pragma unroll
    for (int t = 0; t < 5; ++t)
      out[(size_t)n * 5 + t] = (float)(t + 1) * (d[t] + b2[t]);
  }
}

extern "C" void kernel_launch(void* const* d_in, const int* in_sizes, int n_in, void* d_out,
                              int out_size, void* d_ws, size_t ws_size, hipStream_t stream) {
  auto F = [&](int i) { return (const float*)d_in[i]; };
  const int* edge_index = (const int*)d_in[6];
  const int N_ = in_sizes[0];
  const int E_ = in_sizes[6] / 2;

  char* wsb = (char*)d_ws;
  size_t off = 0;
  auto alloc = [&](size_t bytes) -> char* {
    char* p = wsb + off;
    off += (bytes + 255) & ~(size_t)255;
    return p;
  };
  u16* xh = (u16*)alloc((size_t)N_ * 128 * 2);
  u16* xhA = (u16*)alloc((size_t)N_ * 128 * 2);
  u16* xhB = (u16*)alloc((size_t)N_ * 128 * 2);
  u16* h1n = (u16*)alloc((size_t)N_ * 128 * 2);
  u16* ehP = (u16*)alloc((size_t)E_ * 128 * 2);
  float* aggr = (float*)alloc((size_t)N_ * 128 * 4);
  float* nfeat = (float*)xhA;  // alias (dead before xhA live)
  float* efeat = (float*)xhB;  // alias
  u16* wne2T = (u16*)alloc(16384 * 2);
  u16* wee2T = (u16*)alloc(16384 * 2);
  u16* wpe1T = (u16*)alloc((size_t)9 * 16384 * 2);
  u16* wpe2T = (u16*)alloc((size_t)3 * 16384 * 2);
  u16* wpn1T = (u16*)alloc((size_t)6 * 16384 * 2);
  u16* wpn2T = (u16*)alloc((size_t)3 * 16384 * 2);

  const size_t base_off = off;
  // CSR-path extras
  int* startp = (int*)alloc((size_t)(N_ + 1) * 4);
  int* cntp = (int*)alloc((size_t)N_ * 4);
  int* partp = (int*)alloc((size_t)N_ * 4);
  int* bsump = (int*)alloc(((size_t)(N_ + 255) / 256) * 4 + 256);
  int* sortedS = (int*)alloc((size_t)E_ * 4);
  int* sortedR = (int*)alloc((size_t)E_ * 4);
  bool useCSR = (off <= ws_size);
  if (!useCSR) {
    off = base_off;
    if (off > ws_size) {
      sentinel_kernel<<<(out_size + 255) / 256, 256, 0, stream>>>((float*)d_out, out_size);
      return;
    }
  }

  TArgs ta;
  int ts = 0;
  ta.s[ts++] = {F(13), wne2T};
  ta.s[ts++] = {F(19), wee2T};
  for (int i = 0; i < 3; ++i)
    for (int b = 0; b < 3; ++b)
      ta.s[ts++] = {F(23) + (size_t)(i * 3 + b) * 16384, wpe1T + (size_t)(i * 3 + b) * 16384};
  for (int i = 0; i < 3; ++i) ta.s[ts++] = {F(25) + (size_t)i * 16384, wpe2T + (size_t)i * 16384};
  for (int i = 0; i < 3; ++i)
    for (int b = 0; b < 2; ++b)
      ta.s[ts++] = {F(29) + (size_t)(i * 2 + b) * 16384, wpn1T + (size_t)(i * 2 + b) * 16384};
  for (int i = 0; i < 3; ++i) ta.s[ts++] = {F(31) + (size_t)i * 16384, wpn2T + (size_t)i * 16384};

  const int tilesN = (N_ + 63) / 64;
  const int tilesE = (E_ + 63) / 64;
  const int nb = (N_ + 255) / 256;
  dim3 blk(256);

  transpose_w<<<23, blk, 0, stream>>>(ta);

  const int* sArr = edge_index;
  const int* rArr = edge_index + E_;
  if (useCSR) {
    zero_i32<<<(N_ + 255) / 256, blk, 0, stream>>>(cntp, N_);
    deg_count<<<(E_ + 255) / 256, blk, 0, stream>>>(edge_index, cntp, E_);
    scan1<<<nb, blk, 0, stream>>>(cntp, partp, bsump, N_);
    scan2<<<1, blk, 0, stream>>>(bsump, nb);
    scan3<<<nb, blk, 0, stream>>>(partp, bsump, startp, N_);
    zero_i32<<<(N_ + 255) / 256, blk, 0, stream>>>(cntp, N_);
    fill_slot<<<(E_ + 255) / 256, blk, 0, stream>>>(edge_index, cntp, startp, sortedS, sortedR,
                                                    E_);
    sArr = sortedS;
    rArr = sortedR;
  }

  // ---- encode ----
  node_feat_kernel<<<(N_ + 255) / 256, blk, 0, stream>>>(F(0), F(1), F(2), F(3), F(4), F(7),
                                                         F(8), nfeat, N_);
  enc1_kernel<9><<<(N_ * 128 + 255) / 256, blk, 0, stream>>>(nfeat, F(11), F(12), h1n, N_);
  gemm64<GM_LN, false, false><<<tilesN, blk, 0, stream>>>(h1n, wne2T, nullptr, nullptr, F(14),
                                                          F(15), F(16), nullptr, xh, N_);
  edge_feat_kernel<<<(E_ + 255) / 256, blk, 0, stream>>>(sArr, rArr, F(5), F(0), F(9), F(10),
                                                         efeat, E_);
  enc1_kernel<4><<<(E_ * 128 + 255) / 256, blk, 0, stream>>>(efeat, F(17), F(18), ehP, E_);
  gemm64<GM_LN, false, false><<<tilesE, blk, 0, stream>>>(ehP, wee2T, nullptr, nullptr, F(20),
                                                          F(21), F(22), nullptr, ehP, E_);

  // ---- process steps ----
  for (int i = 0; i < 3; ++i) {
    const u16* wtA = wpe1T + (size_t)(i * 3 + 0) * 16384;
    const u16* wtB = wpe1T + (size_t)(i * 3 + 1) * 16384;
    const u16* wtC = wpe1T + (size_t)(i * 3 + 2) * 16384;
    const float* pb1 = F(24) + i * 128;
    const u16* wt2 = wpe2T + (size_t)i * 16384;
    const float* pb2 = F(26) + i * 128;
    const float* pg = F(27) + i * 128;
    const float* pbe = F(28) + i * 128;
    const u16* wtnA = wpn1T + (size_t)(i * 2 + 0) * 16384;
    const u16* wtnB = wpn1T + (size_t)(i * 2 + 1) * 16384;
    const float* nb1 = F(30) + i * 128;
    const u16* wtn2 = wpn2T + (size_t)i * 16384;
    const float* nb2 = F(32) + i * 128;
    const float* ng = F(33) + i * 128;
    const float* nbe = F(34) + i * 128;

    gemm64_2w<<<tilesN, blk, 0, stream>>>(xh, wtA, wtB, xhA, xhB, N_);
    (void)hipMemsetAsync(aggr, 0, (size_t)N_ * 128 * 4, stream);
    if (useCSR) {
      edge_fused<true><<<tilesE, blk, 0, stream>>>(ehP, xhA, xhB, wtC, pb1, wt2, pb2, pg, pbe,
                                                   sArr, rArr, startp, aggr, E_);
    } else {
      edge_fused<false><<<tilesE, blk, 0, stream>>>(ehP, xhA, xhB, wtC, pb1, wt2, pb2, pg, pbe,
                                                    sArr, rArr, nullptr, aggr, E_);
    }
    gemm64<GM_RELU, true, true><<<tilesN, blk, 0, stream>>>(aggr, wtnA, xh, wtnB, nb1, nullptr,
                                                            nullptr, nullptr, h1n, N_);
    gemm64<GM_LN, false, false><<<tilesN, blk, 0, stream>>>(h1n, wtn2, nullptr, nullptr, nb2,
                                                            ng, nbe, xh, xh, N_);
  }

  // ---- decode ----
  decoder_kernel<<<(N_ + 3) / 4, blk, 0, stream>>>(xh, F(35), F(36), F(37), F(38),
                                                   (float*)d_out, N_);
}